// Round 17
// baseline (256.537 us; speedup 1.0000x reference)
//
#include <hip/hip_runtime.h>
#include <hip/hip_bf16.h>
#include <math.h>

typedef __attribute__((ext_vector_type(8)))  _Float16 f16x8;
typedef __attribute__((ext_vector_type(2)))  __fp16   fp16v2;
typedef __attribute__((ext_vector_type(16))) float    f32x16;

// ---------------------------------------------------------------------------
// GATr forward on MI355X. B=4, N=4096, H=5, BLK=3, INV=32, 16 blades.
// Attention R17: R16 structure (LDS-staged K/V shared by 4 waves, key-split
// across blocks, partials + merge) with (a) nsplit=8 when workspace allows
// (4 blocks/CU) and (b) V slot-swizzle d^((r>>1)&3) fixing the 8-way V-read
// bank conflict down to the inherent 4-way.
// ---------------------------------------------------------------------------

namespace ga {
constexpr int MASKS[16] = {0,1,2,4,8,3,5,6,9,10,12,7,11,13,14,15};
constexpr int popc4(int x){ return (x&1)+((x>>1)&1)+((x>>2)&1)+((x>>3)&1); }
constexpr int idx_of(int m){ int r=-1; for(int i=0;i<16;i++) if(MASKS[i]==m) r=i; return r; }
struct GPTab {
  int cnt[16];
  signed char ii[16][16];
  signed char jj[16][16];
  float ss[16][16];
};
constexpr GPTab make_gptab(){
  GPTab t{};
  for(int i=0;i<16;i++) for(int j=0;j<16;j++){
    int a=MASKS[i], b=MASKS[j];
    if((a&b&1)!=0) continue;           // e0^2 = 0 kills the term
    int sw=0;
    for(int bi=0;bi<4;bi++) if((b>>bi)&1) sw += popc4(a>>(bi+1));
    int k = idx_of(a^b);
    int c = t.cnt[k];
    t.ii[k][c]=(signed char)i; t.jj[k][c]=(signed char)j;
    t.ss[k][c]=(sw&1)? -1.0f : 1.0f;
    t.cnt[k]=c+1;
  }
  return t;
}
} // namespace ga

__device__ const ga::GPTab GPT = ga::make_gptab();
__constant__ int GRADE16[16] = {0,1,1,1,1,2,2,2,2,2,2,3,3,3,3,4};
__constant__ int CPOS16[16] = {0,-1,1,2,3,-1,-1,4,-1,5,6,-1,-1,-1,7,-1};

#define NTOK 16384   // B*N
#define NSEQ 4096
#define NB 4
#define QP 64        // q/k row stride (40 real feats + pads; 128B rows)
#define VTROWS 80    // v tile rows (feats)
#define THR2 11.54f  // defer-max threshold in log2 domain (= 8 nats)

// --------------------------------------------------------------------------
// K1: h[token][o][c] = equi_linear(mv, w_in); mv sparse.
// --------------------------------------------------------------------------
__global__ __launch_bounds__(256) void k_init_h(
    const float* __restrict__ x, const float* __restrict__ w_in,
    float* __restrict__ h)
{
  int gid = blockIdx.x*256 + threadIdx.x;      // token*5 + o
  if (gid >= NTOK*5) return;
  int o = gid % 5, token = gid / 5;
  const float* xt = x + (size_t)token*35;
  const float* w0 = w_in + o*32;               // grade-0 block, row o
  float s = w0[0];                             // mv[0][0] = 1.0
  #pragma unroll
  for (int i=1;i<32;i++) s += w0[i]*xt[i];
  float w2c = w_in[2*160 + o*32 + 0];          // grade-2, input channel 0
  float* ht = h + (size_t)token*80 + o*16;
  #pragma unroll
  for (int c=0;c<16;c++) ht[c] = 0.f;
  ht[0] = s;
  ht[5] = w2c*xt[32];
  ht[6] = w2c*xt[33];
  ht[8] = w2c*xt[34];
}

// --------------------------------------------------------------------------
// K2: fused equi_layernorm + q,k,v equi_linear -> fp16 staging.
// q/k: [token][64]; q pre-scaled by scale*log2(e).
// v: TILE-MAJOR vt[b][tile][feat(80)][col], key->col permuted (pi).
// --------------------------------------------------------------------------
__global__ __launch_bounds__(256) void k_ln_qkv(
    const float* __restrict__ h,
    const float* __restrict__ wq, const float* __restrict__ wk,
    const float* __restrict__ wv,
    _Float16* __restrict__ qf, _Float16* __restrict__ kf,
    _Float16* __restrict__ vf)
{
  int tid = threadIdx.x;
  int c   = tid & 15;
  int token = blockIdx.x*16 + (tid>>4);
  int b = token >> 12;          // /4096
  int n = token & 4095;
  int vt_tile = b*128 + (n>>5);
  int nn = n & 31;
  int t  = (nn>>2)&3;
  int t2 = ((t<<1)|(t>>1))&3;             // 0,3 fixed; 1<->2
  int vt_col = (nn&3) | (t2<<2) | (nn&16);
  const float* ht = h + (size_t)token*80;
  float hv[5];
  #pragma unroll
  for (int i=0;i<5;i++) hv[i] = ht[i*16 + c];
  bool inner = (0x469D >> c) & 1;
  float part = 0.f;
  if (inner) {
    #pragma unroll
    for (int i=0;i<5;i++) part += hv[i]*hv[i];
  }
  part += __shfl_xor(part, 1);
  part += __shfl_xor(part, 2);
  part += __shfl_xor(part, 4);
  part += __shfl_xor(part, 8);
  float denom = sqrtf(part*(1.f/80.f) + 1e-6f);
  float rinv = 1.f/denom;
  float rln[5];
  #pragma unroll
  for (int i=0;i<5;i++) rln[i] = hv[i]*rinv;

  int g = GRADE16[c];
  int cp = CPOS16[c];
  const float scaleq = 0.16129820906f;   // (1/sqrt(80)) * log2(e)
  #pragma unroll
  for (int o=0;o<5;o++) {
    const float* wqr = wq + g*25 + o*5;
    const float* wkr = wk + g*25 + o*5;
    const float* wvr = wv + g*25 + o*5;
    float aq=0.f, ak=0.f, av=0.f;
    #pragma unroll
    for (int i=0;i<5;i++) {
      aq += rln[i]*wqr[i];
      ak += rln[i]*wkr[i];
      av += rln[i]*wvr[i];
    }
    vf[((size_t)vt_tile*VTROWS + o*16 + c)*32 + vt_col] = (_Float16)av;
    if (inner) {
      size_t qo = (size_t)token*QP + o*8 + cp;
      qf[qo] = (_Float16)(aq*scaleq);
      kf[qo] = (_Float16)ak;
    }
  }
  if (c < 8) {
    size_t po = (size_t)token*QP + 40 + c;
    qf[po] = (_Float16)0.f;
    kf[po] = (_Float16)0.f;
  }
}

// --------------------------------------------------------------------------
// K3: LDS-staged flash attention (R16 structure; V slot-swizzle improved).
// Block = 256 thr = 4 waves; each wave owns a DIFFERENT 32-row Q-tile; all
// share the SAME key range. K (4KB) + V (5KB) per tile staged once per
// block, double-buffered, 1 barrier/tile. Swapped QK^T; pi-permuted V.
// V store slot = d ^ ((row>>1)&3)  (4-way-minimal bank spread).
// Epilogue: raw per-wave partials (O, m, l) -> merge kernel.
// --------------------------------------------------------------------------
__global__ __launch_bounds__(256, 2) void k_attn_lds(
    const _Float16* __restrict__ qf, const _Float16* __restrict__ kf,
    const _Float16* __restrict__ vf,
    float* __restrict__ wsO, float* __restrict__ wsM,
    float* __restrict__ wsL, int nsplit)
{
  __shared__ __align__(16) char sK[2][4096];
  __shared__ __align__(16) char sV[2][5120];
  __shared__ __align__(16) float sF[4][32];
  int tid = threadIdx.x;
  int w  = tid >> 6;
  int l  = tid & 63;
  int ln = l & 31;
  int hf = l >> 5;
  int bid = blockIdx.x;
  int xcd = bid & 7;
  int b   = xcd & 3;
  int rest = bid >> 3;
  int qlo  = rest & 15;                   // 16 q-lo groups
  int z    = rest >> 4;                   // 0..nsplit-1
  int qgroup = (xcd>>2)*16 + qlo;         // 0..31
  int qtile = qgroup*4 + w;               // 0..127 (per batch)
  int rowbase = b*NSEQ + qtile*32;
  int ntiles = (NSEQ/nsplit) >> 5;
  int kbeg = z*(NSEQ/nsplit);

  // Q frags (B operand): j=lane&31=qrow, k=(lane>>5)*8+e
  const _Float16* qp = qf + (size_t)(rowbase + ln)*QP + hf*8;
  f16x8 q0 = *(const f16x8*)(qp);
  f16x8 q1 = *(const f16x8*)(qp + 16);
  f16x8 q2 = *(const f16x8*)(qp + 32);

  f32x16 acc0, acc1, acc2;
  #pragma unroll
  for (int r=0;r<16;r++){ acc0[r]=0.f; acc1[r]=0.f; acc2[r]=0.f; }
  float m = -1e30f, lsum = 0.f;

  // swizzled ds_read byte offsets (fixed per lane)
  int rdK0 = ln*128 + (((0+hf)^(ln&7))<<4);
  int rdK1 = ln*128 + (((2+hf)^(ln&7))<<4);
  int rdK2 = ln*128 + (((4+hf)^(ln&7))<<4);
  int vr0 = ln, vr1 = 32+ln, vr2 = 64+(ln&15);
  int sw0 = (vr0>>1)&3, sw1 = (vr1>>1)&3, sw2 = (vr2>>1)&3;
  int rdV00 = vr0*64 + (((hf  )^sw0)<<4);
  int rdV01 = vr0*64 + (((hf+2)^sw0)<<4);
  int rdV10 = vr1*64 + (((hf  )^sw1)<<4);
  int rdV11 = vr1*64 + (((hf+2)^sw1)<<4);
  int rdV20 = vr2*64 + (((hf  )^sw2)<<4);
  int rdV21 = vr2*64 + (((hf+2)^sw2)<<4);

  const _Float16* kfb = kf + (size_t)b*NSEQ*QP;
  const _Float16* vfb = vf + (size_t)(b*128)*(VTROWS*32);

  // ---- prologue: stage tile 0 into buf 0 ----
  {
    const float4* kT = (const float4*)(kfb + (size_t)kbeg*QP);
    const float4* vT = (const float4*)(vfb + (size_t)(kbeg>>5)*(VTROWS*32));
    #pragma unroll
    for (int i=w; i<9; i+=4) {
      float4 d = (i<4) ? kT[i*64 + l] : vT[(i-4)*64 + l];
      if (i<4) {
        int gid = i*64 + l;
        *(float4*)(sK[0] + ((gid>>3)*128 + (((gid&7)^((gid>>3)&7))<<4))) = d;
      } else {
        int gid = (i-4)*64 + l;
        *(float4*)(sV[0] + ((gid>>2)*64 + (((gid&3)^((gid>>3)&3))<<4))) = d;
      }
    }
  }
  __syncthreads();

  for (int t=0; t<ntiles; ++t) {
    int cur = t & 1;
    // issue global loads for tile t+1 (into regs; written to LDS later)
    float4 stg0, stg1, stg2; int i2=-1;
    if (t+1 < ntiles) {
      int koffn = kbeg + (t+1)*32;
      const float4* kT = (const float4*)(kfb + (size_t)koffn*QP);
      const float4* vT = (const float4*)(vfb + (size_t)(koffn>>5)*(VTROWS*32));
      stg0 = kT[w*64+l];
      stg1 = vT[w*64+l];
      if (w==0) { i2 = 8; stg2 = vT[4*64+l]; }
    }

    // ds_read K frags (swizzled)
    f16x8 kc0 = *(const f16x8*)(sK[cur] + rdK0);
    f16x8 kc1 = *(const f16x8*)(sK[cur] + rdK1);
    f16x8 kc2 = *(const f16x8*)(sK[cur] + rdK2);

    // QK^T
    f32x16 S;
    #pragma unroll
    for (int r=0;r<16;r++) S[r]=0.f;
    S = __builtin_amdgcn_mfma_f32_32x32x16_f16(kc0, q0, S, 0,0,0);
    S = __builtin_amdgcn_mfma_f32_32x32x16_f16(kc1, q1, S, 0,0,0);
    S = __builtin_amdgcn_mfma_f32_32x32x16_f16(kc2, q2, S, 0,0,0);

    // tile max: balanced tree
    float t01 = fmaxf(S[0],S[1]),   t23 = fmaxf(S[2],S[3]);
    float t45 = fmaxf(S[4],S[5]),   t67 = fmaxf(S[6],S[7]);
    float t89 = fmaxf(S[8],S[9]),   tab = fmaxf(S[10],S[11]);
    float tcd = fmaxf(S[12],S[13]), tef = fmaxf(S[14],S[15]);
    float u0 = fmaxf(t01,t23), u1 = fmaxf(t45,t67);
    float u2 = fmaxf(t89,tab), u3 = fmaxf(tcd,tef);
    float tmax = fmaxf(fmaxf(u0,u1), fmaxf(u2,u3));
    tmax = fmaxf(tmax, __shfl_xor(tmax, 32));
    if (!__all(tmax <= m + THR2)) {
      float mn = fmaxf(m, tmax);
      float f = exp2f(m - mn);
      lsum *= f;
      m = mn;
      if (hf==0) sF[w][ln] = f;
      float fv[16];
      *(float4*)&fv[0]  = *(const float4*)&sF[w][ 0 + hf*4];
      *(float4*)&fv[4]  = *(const float4*)&sF[w][ 8 + hf*4];
      *(float4*)&fv[8]  = *(const float4*)&sF[w][16 + hf*4];
      *(float4*)&fv[12] = *(const float4*)&sF[w][24 + hf*4];
      #pragma unroll
      for (int r=0;r<16;r++){ float fr=fv[r]; acc0[r]*=fr; acc1[r]*=fr; acc2[r]*=fr; }
    }
    float p[16];
    #pragma unroll
    for (int r=0;r<16;r++) p[r] = exp2f(S[r] - m);
    float s0 = (p[0]+p[1]) + (p[2]+p[3]);
    float s1 = (p[4]+p[5]) + (p[6]+p[7]);
    float s2 = (p[8]+p[9]) + (p[10]+p[11]);
    float s3 = (p[12]+p[13]) + (p[14]+p[15]);
    lsum += (s0+s1) + (s2+s3);

    // pack P -> fp16 A-frags: LOCAL pack (pi-permuted V cols)
    union { unsigned u[4]; f16x8 v; } A0, A1;
    #pragma unroll
    for (int e=0;e<4;e++) {
      union { fp16v2 h2; unsigned u; } cv;
      cv.h2 = __builtin_amdgcn_cvt_pkrtz(p[2*e], p[2*e+1]);
      A0.u[e] = cv.u;
    }
    #pragma unroll
    for (int e=0;e<4;e++) {
      union { fp16v2 h2; unsigned u; } cv;
      cv.h2 = __builtin_amdgcn_cvt_pkrtz(p[8+2*e], p[9+2*e]);
      A1.u[e] = cv.u;
    }

    // ds_read V frags (swizzled)
    f16x8 vc00 = *(const f16x8*)(sV[cur] + rdV00);
    f16x8 vc01 = *(const f16x8*)(sV[cur] + rdV01);
    f16x8 vc10 = *(const f16x8*)(sV[cur] + rdV10);
    f16x8 vc11 = *(const f16x8*)(sV[cur] + rdV11);
    f16x8 vc20 = *(const f16x8*)(sV[cur] + rdV20);
    f16x8 vc21 = *(const f16x8*)(sV[cur] + rdV21);

    acc0 = __builtin_amdgcn_mfma_f32_32x32x16_f16(A0.v, vc00, acc0, 0,0,0);
    acc0 = __builtin_amdgcn_mfma_f32_32x32x16_f16(A1.v, vc01, acc0, 0,0,0);
    acc1 = __builtin_amdgcn_mfma_f32_32x32x16_f16(A0.v, vc10, acc1, 0,0,0);
    acc1 = __builtin_amdgcn_mfma_f32_32x32x16_f16(A1.v, vc11, acc1, 0,0,0);
    acc2 = __builtin_amdgcn_mfma_f32_32x32x16_f16(A0.v, vc20, acc2, 0,0,0);
    acc2 = __builtin_amdgcn_mfma_f32_32x32x16_f16(A1.v, vc21, acc2, 0,0,0);

    // ds_write staged tile t+1 (other buffer)
    if (t+1 < ntiles) {
      int nxt = (t+1) & 1;
      {
        int gid = w*64 + l;
        *(float4*)(sK[nxt] + ((gid>>3)*128 + (((gid&7)^((gid>>3)&7))<<4))) = stg0;
      }
      {
        int gid = w*64 + l;
        *(float4*)(sV[nxt] + ((gid>>2)*64 + (((gid&3)^((gid>>3)&3))<<4))) = stg1;
      }
      if (i2 == 8) {
        int gid = 4*64 + l;
        *(float4*)(sV[nxt] + ((gid>>2)*64 + (((gid&3)^((gid>>3)&3))<<4))) = stg2;
      }
    }
    __syncthreads();
  }

  // merge per-half lsum partials
  lsum += __shfl_xor(lsum, 32);

  // epilogue: write raw per-wave partials
  int pidx = (b*128 + qtile)*nsplit + z;
  if (hf==0) {
    wsM[pidx*32 + ln] = m;
    wsL[pidx*32 + ln] = lsum;
  }
  float* po = wsO + (size_t)pidx*32*80;
  #pragma unroll
  for (int r=0;r<16;r++) {
    int row = (r&3) + 8*(r>>2) + 4*hf;
    po[row*80 + ln]      = acc0[r];
    po[row*80 + 32 + ln] = acc1[r];
    if (ln < 16) po[row*80 + 64 + ln] = acc2[r];
  }
}

// --------------------------------------------------------------------------
// K3b: merge nsplit key-splits + wo-projection + residual into h.
// --------------------------------------------------------------------------
__global__ __launch_bounds__(256) void k_merge_proj(
    const float* __restrict__ wsO, const float* __restrict__ wsM,
    const float* __restrict__ wsL, const float* __restrict__ wo,
    float* __restrict__ h, int nsplit)
{
  int tid = threadIdx.x;
  int c   = tid & 15;
  int token = blockIdx.x*16 + (tid>>4);
  int qrow = token & 31;
  int qt   = token >> 5;              // global q-tile (0..511)
  int base = qt*nsplit;
  float M = -1e30f;
  for (int s=0; s<nsplit; ++s) M = fmaxf(M, wsM[(base+s)*32 + qrow]);
  float wgt[8];
  float L = 0.f;
  for (int s=0; s<nsplit; ++s) {
    wgt[s] = exp2f(wsM[(base+s)*32 + qrow] - M);
    L += wgt[s]*wsL[(base+s)*32 + qrow];
  }
  float invL = 1.f/L;
  float att[5];
  #pragma unroll
  for (int i=0;i<5;i++) {
    float a = 0.f;
    for (int s=0; s<nsplit; ++s)
      a += wgt[s]*wsO[((size_t)(base+s)*32 + qrow)*80 + i*16 + c];
    att[i] = a*invL;
  }
  int g = GRADE16[c];
  float* ht = h + (size_t)token*80;
  #pragma unroll
  for (int o=0;o<5;o++) {
    const float* wor = wo + g*25 + o*5;
    float a = 0.f;
    #pragma unroll
    for (int i=0;i<5;i++) a += att[i]*wor[i];
    ht[o*16 + c] += a;
  }
}

// --------------------------------------------------------------------------
// K4: fused equi_layernorm + MLP + residual.
// --------------------------------------------------------------------------
__global__ __launch_bounds__(256) void k_mlp(
    float* __restrict__ h,
    const float* __restrict__ w1, const float* __restrict__ w2)
{
  __shared__ float sh1[16][10][16];
  int tid = threadIdx.x;
  int c   = tid & 15;
  int tl  = tid >> 4;
  int token = blockIdx.x*16 + tl;
  float* ht = h + (size_t)token*80;
  float hv[5];
  #pragma unroll
  for (int i=0;i<5;i++) hv[i] = ht[i*16 + c];
  bool inner = (0x469D >> c) & 1;
  float part = 0.f;
  if (inner) {
    #pragma unroll
    for (int i=0;i<5;i++) part += hv[i]*hv[i];
  }
  part += __shfl_xor(part, 1);
  part += __shfl_xor(part, 2);
  part += __shfl_xor(part, 4);
  part += __shfl_xor(part, 8);
  float denom = sqrtf(part*(1.f/80.f) + 1e-6f);
  float rinv = 1.f/denom;
  float rln[5];
  #pragma unroll
  for (int i=0;i<5;i++) rln[i] = hv[i]*rinv;

  int g = GRADE16[c];
  #pragma unroll
  for (int o=0;o<10;o++) {
    const float* w1r = w1 + g*50 + o*5;
    float a=0.f;
    #pragma unroll
    for (int i=0;i<5;i++) a += rln[i]*w1r[i];
    sh1[tl][o][c] = a;
  }
  __syncthreads();
  float gpv[5];
  #pragma unroll
  for (int hh=0; hh<5; hh++) {
    float a = 0.f;
    int n = GPT.cnt[c];
    for (int e=0; e<n; ++e) {
      a += GPT.ss[c][e]*sh1[tl][hh][GPT.ii[c][e]]*sh1[tl][5+hh][GPT.jj[c][e]];
    }
    gpv[hh] = a;
  }
  int base = (tid & 63) & ~15;
  #pragma unroll
  for (int hh=0;hh<5;hh++) {
    float g0 = __shfl(gpv[hh], base);
    float u  = 0.7978845608028654f*(g0 + 0.044715f*g0*g0*g0);
    float gate = 0.5f*g0*(1.f + tanhf(u));
    gpv[hh] *= gate;
  }
  #pragma unroll
  for (int o=0;o<5;o++) {
    const float* w2r = w2 + g*25 + o*5;
    float a=0.f;
    #pragma unroll
    for (int i=0;i<5;i++) a += gpv[i]*w2r[i];
    ht[o*16+c] += a;
  }
}

// --------------------------------------------------------------------------
// K5: final equi_linear (w_out) + output extraction.
// --------------------------------------------------------------------------
__global__ __launch_bounds__(256) void k_out(
    const float* __restrict__ h, const float* __restrict__ w_out,
    float* __restrict__ out)
{
  int gid = blockIdx.x*256 + threadIdx.x;
  if (gid >= NTOK*35) return;
  int j = gid % 35, token = gid / 35;
  const float* ht = h + (size_t)token*80;
  float a = 0.f;
  if (j < 32) {
    const float* w = w_out + j*5;              // grade 0, row j
    #pragma unroll
    for (int i=0;i<5;i++) a += ht[i*16 + 0]*w[i];
  } else {
    int c = (j==32)?5:((j==33)?6:8);
    const float* w = w_out + 2*160 + 0*5;      // grade 2, row 0
    #pragma unroll
    for (int i=0;i<5;i++) a += ht[i*16 + c]*w[i];
  }
  out[gid] = a;
}

// --------------------------------------------------------------------------
extern "C" void kernel_launch(void* const* d_in, const int* in_sizes, int n_in,
                              void* d_out, int out_size, void* d_ws, size_t ws_size,
                              hipStream_t stream) {
  const float* x     = (const float*)d_in[0];
  const float* w_in  = (const float*)d_in[1];
  const float* w_out = (const float*)d_in[2];
  const float* wq    = (const float*)d_in[3];
  const float* wk    = (const float*)d_in[4];
  const float* wv    = (const float*)d_in[5];
  const float* wo    = (const float*)d_in[6];
  const float* w1    = (const float*)d_in[7];
  const float* w2    = (const float*)d_in[8];
  float* out = (float*)d_out;

  // carve: h fp32 + qf,kf fp16[64/row] + vf fp16 tiled + nsplit partials
  char* p = (char*)d_ws;
  float* h = (float*)p;              p += (size_t)NTOK*80*4;
  _Float16* qf = (_Float16*)p;       p += (size_t)NTOK*QP*2;
  _Float16* kf = (_Float16*)p;       p += (size_t)NTOK*QP*2;
  _Float16* vf = (_Float16*)p;       p += (size_t)NB*128*VTROWS*32*2;
  size_t fixed = (size_t)((char*)p - (char*)d_ws);
  int nsplit = 8;
  if (fixed + (size_t)512*8*32*(80+2)*4 > ws_size) nsplit = 4;
  if (fixed + (size_t)512*4*32*(80+2)*4 > ws_size) nsplit = 2;
  float* wsO = (float*)p;            p += (size_t)512*nsplit*32*80*4;
  float* wsM = (float*)p;            p += (size_t)512*nsplit*32*4;
  float* wsL = (float*)p;

  k_init_h<<<(NTOK*5 + 255)/256, 256, 0, stream>>>(x, w_in, h);
  for (int blk=0; blk<3; ++blk) {
    k_ln_qkv<<<NTOK/16, 256, 0, stream>>>(h, wq+blk*125, wk+blk*125, wv+blk*125,
                                          qf, kf, vf);
    k_attn_lds<<<128*nsplit, 256, 0, stream>>>(qf, kf, vf, wsO, wsM, wsL, nsplit);
    k_merge_proj<<<NTOK/16, 256, 0, stream>>>(wsO, wsM, wsL, wo+blk*125, h, nsplit);
    k_mlp<<<NTOK/16, 256, 0, stream>>>(h, w1+blk*250, w2+blk*125);
  }
  k_out<<<(NTOK*35 + 255)/256, 256, 0, stream>>>(h, w_out, out);
}

// Round 18
// 241.974 us; speedup vs baseline: 1.0602x; 1.0602x over previous
//
#include <hip/hip_runtime.h>
#include <hip/hip_bf16.h>
#include <math.h>

typedef __attribute__((ext_vector_type(8)))  _Float16 f16x8;
typedef __attribute__((ext_vector_type(2)))  __fp16   fp16v2;
typedef __attribute__((ext_vector_type(16))) float    f32x16;

// ---------------------------------------------------------------------------
// GATr forward on MI355X. B=4, N=4096, H=5, BLK=3, INV=32, 16 blades.
// Attention R18: R16 structure (LDS-staged K/V shared by 4 waves, nsplit=4
// key-splits -> 2 blocks/CU, partials + merge) + R17's improved V
// slot-swizzle d^((r>>1)&3) (4-way-minimal bank conflicts).
// ---------------------------------------------------------------------------

namespace ga {
constexpr int MASKS[16] = {0,1,2,4,8,3,5,6,9,10,12,7,11,13,14,15};
constexpr int popc4(int x){ return (x&1)+((x>>1)&1)+((x>>2)&1)+((x>>3)&1); }
constexpr int idx_of(int m){ int r=-1; for(int i=0;i<16;i++) if(MASKS[i]==m) r=i; return r; }
struct GPTab {
  int cnt[16];
  signed char ii[16][16];
  signed char jj[16][16];
  float ss[16][16];
};
constexpr GPTab make_gptab(){
  GPTab t{};
  for(int i=0;i<16;i++) for(int j=0;j<16;j++){
    int a=MASKS[i], b=MASKS[j];
    if((a&b&1)!=0) continue;           // e0^2 = 0 kills the term
    int sw=0;
    for(int bi=0;bi<4;bi++) if((b>>bi)&1) sw += popc4(a>>(bi+1));
    int k = idx_of(a^b);
    int c = t.cnt[k];
    t.ii[k][c]=(signed char)i; t.jj[k][c]=(signed char)j;
    t.ss[k][c]=(sw&1)? -1.0f : 1.0f;
    t.cnt[k]=c+1;
  }
  return t;
}
} // namespace ga

__device__ const ga::GPTab GPT = ga::make_gptab();
__constant__ int GRADE16[16] = {0,1,1,1,1,2,2,2,2,2,2,3,3,3,3,4};
__constant__ int CPOS16[16] = {0,-1,1,2,3,-1,-1,4,-1,5,6,-1,-1,-1,7,-1};

#define NTOK 16384   // B*N
#define NSEQ 4096
#define NB 4
#define QP 64        // q/k row stride (40 real feats + pads; 128B rows)
#define VTROWS 80    // v tile rows (feats)
#define THR2 11.54f  // defer-max threshold in log2 domain (= 8 nats)

// --------------------------------------------------------------------------
// K1: h[token][o][c] = equi_linear(mv, w_in); mv sparse.
// --------------------------------------------------------------------------
__global__ __launch_bounds__(256) void k_init_h(
    const float* __restrict__ x, const float* __restrict__ w_in,
    float* __restrict__ h)
{
  int gid = blockIdx.x*256 + threadIdx.x;      // token*5 + o
  if (gid >= NTOK*5) return;
  int o = gid % 5, token = gid / 5;
  const float* xt = x + (size_t)token*35;
  const float* w0 = w_in + o*32;               // grade-0 block, row o
  float s = w0[0];                             // mv[0][0] = 1.0
  #pragma unroll
  for (int i=1;i<32;i++) s += w0[i]*xt[i];
  float w2c = w_in[2*160 + o*32 + 0];          // grade-2, input channel 0
  float* ht = h + (size_t)token*80 + o*16;
  #pragma unroll
  for (int c=0;c<16;c++) ht[c] = 0.f;
  ht[0] = s;
  ht[5] = w2c*xt[32];
  ht[6] = w2c*xt[33];
  ht[8] = w2c*xt[34];
}

// --------------------------------------------------------------------------
// K2: fused equi_layernorm + q,k,v equi_linear -> fp16 staging.
// q/k: [token][64]; q pre-scaled by scale*log2(e).
// v: TILE-MAJOR vt[b][tile][feat(80)][col], key->col permuted (pi).
// --------------------------------------------------------------------------
__global__ __launch_bounds__(256) void k_ln_qkv(
    const float* __restrict__ h,
    const float* __restrict__ wq, const float* __restrict__ wk,
    const float* __restrict__ wv,
    _Float16* __restrict__ qf, _Float16* __restrict__ kf,
    _Float16* __restrict__ vf)
{
  int tid = threadIdx.x;
  int c   = tid & 15;
  int token = blockIdx.x*16 + (tid>>4);
  int b = token >> 12;          // /4096
  int n = token & 4095;
  int vt_tile = b*128 + (n>>5);
  int nn = n & 31;
  int t  = (nn>>2)&3;
  int t2 = ((t<<1)|(t>>1))&3;             // 0,3 fixed; 1<->2
  int vt_col = (nn&3) | (t2<<2) | (nn&16);
  const float* ht = h + (size_t)token*80;
  float hv[5];
  #pragma unroll
  for (int i=0;i<5;i++) hv[i] = ht[i*16 + c];
  bool inner = (0x469D >> c) & 1;
  float part = 0.f;
  if (inner) {
    #pragma unroll
    for (int i=0;i<5;i++) part += hv[i]*hv[i];
  }
  part += __shfl_xor(part, 1);
  part += __shfl_xor(part, 2);
  part += __shfl_xor(part, 4);
  part += __shfl_xor(part, 8);
  float denom = sqrtf(part*(1.f/80.f) + 1e-6f);
  float rinv = 1.f/denom;
  float rln[5];
  #pragma unroll
  for (int i=0;i<5;i++) rln[i] = hv[i]*rinv;

  int g = GRADE16[c];
  int cp = CPOS16[c];
  const float scaleq = 0.16129820906f;   // (1/sqrt(80)) * log2(e)
  #pragma unroll
  for (int o=0;o<5;o++) {
    const float* wqr = wq + g*25 + o*5;
    const float* wkr = wk + g*25 + o*5;
    const float* wvr = wv + g*25 + o*5;
    float aq=0.f, ak=0.f, av=0.f;
    #pragma unroll
    for (int i=0;i<5;i++) {
      aq += rln[i]*wqr[i];
      ak += rln[i]*wkr[i];
      av += rln[i]*wvr[i];
    }
    vf[((size_t)vt_tile*VTROWS + o*16 + c)*32 + vt_col] = (_Float16)av;
    if (inner) {
      size_t qo = (size_t)token*QP + o*8 + cp;
      qf[qo] = (_Float16)(aq*scaleq);
      kf[qo] = (_Float16)ak;
    }
  }
  if (c < 8) {
    size_t po = (size_t)token*QP + 40 + c;
    qf[po] = (_Float16)0.f;
    kf[po] = (_Float16)0.f;
  }
}

// --------------------------------------------------------------------------
// K3: LDS-staged flash attention (R16 structure; R17 V slot-swizzle).
// Block = 256 thr = 4 waves; each wave owns a DIFFERENT 32-row Q-tile; all
// share the SAME key range. K (4KB) + V (5KB) per tile staged once per
// block, double-buffered, 1 barrier/tile. Swapped QK^T; pi-permuted V.
// V store slot = d ^ ((row>>1)&3)  (4-way-minimal bank spread).
// Epilogue: raw per-wave partials (O, m, l) -> merge kernel.
// --------------------------------------------------------------------------
__global__ __launch_bounds__(256, 2) void k_attn_lds(
    const _Float16* __restrict__ qf, const _Float16* __restrict__ kf,
    const _Float16* __restrict__ vf,
    float* __restrict__ wsO, float* __restrict__ wsM,
    float* __restrict__ wsL, int nsplit)
{
  __shared__ __align__(16) char sK[2][4096];
  __shared__ __align__(16) char sV[2][5120];
  __shared__ __align__(16) float sF[4][32];
  int tid = threadIdx.x;
  int w  = tid >> 6;
  int l  = tid & 63;
  int ln = l & 31;
  int hf = l >> 5;
  int bid = blockIdx.x;
  int xcd = bid & 7;
  int b   = xcd & 3;
  int rest = bid >> 3;
  int qlo  = rest & 15;                   // 16 q-lo groups
  int z    = rest >> 4;                   // 0..nsplit-1
  int qgroup = (xcd>>2)*16 + qlo;         // 0..31
  int qtile = qgroup*4 + w;               // 0..127 (per batch)
  int rowbase = b*NSEQ + qtile*32;
  int ntiles = (NSEQ/nsplit) >> 5;
  int kbeg = z*(NSEQ/nsplit);

  // Q frags (B operand): j=lane&31=qrow, k=(lane>>5)*8+e
  const _Float16* qp = qf + (size_t)(rowbase + ln)*QP + hf*8;
  f16x8 q0 = *(const f16x8*)(qp);
  f16x8 q1 = *(const f16x8*)(qp + 16);
  f16x8 q2 = *(const f16x8*)(qp + 32);

  f32x16 acc0, acc1, acc2;
  #pragma unroll
  for (int r=0;r<16;r++){ acc0[r]=0.f; acc1[r]=0.f; acc2[r]=0.f; }
  float m = -1e30f, lsum = 0.f;

  // swizzled ds_read byte offsets (fixed per lane)
  int rdK0 = ln*128 + (((0+hf)^(ln&7))<<4);
  int rdK1 = ln*128 + (((2+hf)^(ln&7))<<4);
  int rdK2 = ln*128 + (((4+hf)^(ln&7))<<4);
  int vr0 = ln, vr1 = 32+ln, vr2 = 64+(ln&15);
  int sw0 = (vr0>>1)&3, sw1 = (vr1>>1)&3, sw2 = (vr2>>1)&3;
  int rdV00 = vr0*64 + (((hf  )^sw0)<<4);
  int rdV01 = vr0*64 + (((hf+2)^sw0)<<4);
  int rdV10 = vr1*64 + (((hf  )^sw1)<<4);
  int rdV11 = vr1*64 + (((hf+2)^sw1)<<4);
  int rdV20 = vr2*64 + (((hf  )^sw2)<<4);
  int rdV21 = vr2*64 + (((hf+2)^sw2)<<4);

  const _Float16* kfb = kf + (size_t)b*NSEQ*QP;
  const _Float16* vfb = vf + (size_t)(b*128)*(VTROWS*32);

  // ---- prologue: stage tile 0 into buf 0 ----
  {
    const float4* kT = (const float4*)(kfb + (size_t)kbeg*QP);
    const float4* vT = (const float4*)(vfb + (size_t)(kbeg>>5)*(VTROWS*32));
    #pragma unroll
    for (int i=w; i<9; i+=4) {
      float4 d = (i<4) ? kT[i*64 + l] : vT[(i-4)*64 + l];
      if (i<4) {
        int gid = i*64 + l;
        *(float4*)(sK[0] + ((gid>>3)*128 + (((gid&7)^((gid>>3)&7))<<4))) = d;
      } else {
        int gid = (i-4)*64 + l;
        *(float4*)(sV[0] + ((gid>>2)*64 + (((gid&3)^((gid>>3)&3))<<4))) = d;
      }
    }
  }
  __syncthreads();

  for (int t=0; t<ntiles; ++t) {
    int cur = t & 1;
    // issue global loads for tile t+1 (into regs; written to LDS later)
    float4 stg0, stg1, stg2; int i2=-1;
    if (t+1 < ntiles) {
      int koffn = kbeg + (t+1)*32;
      const float4* kT = (const float4*)(kfb + (size_t)koffn*QP);
      const float4* vT = (const float4*)(vfb + (size_t)(koffn>>5)*(VTROWS*32));
      stg0 = kT[w*64+l];
      stg1 = vT[w*64+l];
      if (w==0) { i2 = 8; stg2 = vT[4*64+l]; }
    }

    // ds_read K frags (swizzled)
    f16x8 kc0 = *(const f16x8*)(sK[cur] + rdK0);
    f16x8 kc1 = *(const f16x8*)(sK[cur] + rdK1);
    f16x8 kc2 = *(const f16x8*)(sK[cur] + rdK2);

    // QK^T
    f32x16 S;
    #pragma unroll
    for (int r=0;r<16;r++) S[r]=0.f;
    S = __builtin_amdgcn_mfma_f32_32x32x16_f16(kc0, q0, S, 0,0,0);
    S = __builtin_amdgcn_mfma_f32_32x32x16_f16(kc1, q1, S, 0,0,0);
    S = __builtin_amdgcn_mfma_f32_32x32x16_f16(kc2, q2, S, 0,0,0);

    // tile max: balanced tree
    float t01 = fmaxf(S[0],S[1]),   t23 = fmaxf(S[2],S[3]);
    float t45 = fmaxf(S[4],S[5]),   t67 = fmaxf(S[6],S[7]);
    float t89 = fmaxf(S[8],S[9]),   tab = fmaxf(S[10],S[11]);
    float tcd = fmaxf(S[12],S[13]), tef = fmaxf(S[14],S[15]);
    float u0 = fmaxf(t01,t23), u1 = fmaxf(t45,t67);
    float u2 = fmaxf(t89,tab), u3 = fmaxf(tcd,tef);
    float tmax = fmaxf(fmaxf(u0,u1), fmaxf(u2,u3));
    tmax = fmaxf(tmax, __shfl_xor(tmax, 32));
    if (!__all(tmax <= m + THR2)) {
      float mn = fmaxf(m, tmax);
      float f = exp2f(m - mn);
      lsum *= f;
      m = mn;
      if (hf==0) sF[w][ln] = f;
      float fv[16];
      *(float4*)&fv[0]  = *(const float4*)&sF[w][ 0 + hf*4];
      *(float4*)&fv[4]  = *(const float4*)&sF[w][ 8 + hf*4];
      *(float4*)&fv[8]  = *(const float4*)&sF[w][16 + hf*4];
      *(float4*)&fv[12] = *(const float4*)&sF[w][24 + hf*4];
      #pragma unroll
      for (int r=0;r<16;r++){ float fr=fv[r]; acc0[r]*=fr; acc1[r]*=fr; acc2[r]*=fr; }
    }
    float p[16];
    #pragma unroll
    for (int r=0;r<16;r++) p[r] = exp2f(S[r] - m);
    float s0 = (p[0]+p[1]) + (p[2]+p[3]);
    float s1 = (p[4]+p[5]) + (p[6]+p[7]);
    float s2 = (p[8]+p[9]) + (p[10]+p[11]);
    float s3 = (p[12]+p[13]) + (p[14]+p[15]);
    lsum += (s0+s1) + (s2+s3);

    // pack P -> fp16 A-frags: LOCAL pack (pi-permuted V cols)
    union { unsigned u[4]; f16x8 v; } A0, A1;
    #pragma unroll
    for (int e=0;e<4;e++) {
      union { fp16v2 h2; unsigned u; } cv;
      cv.h2 = __builtin_amdgcn_cvt_pkrtz(p[2*e], p[2*e+1]);
      A0.u[e] = cv.u;
    }
    #pragma unroll
    for (int e=0;e<4;e++) {
      union { fp16v2 h2; unsigned u; } cv;
      cv.h2 = __builtin_amdgcn_cvt_pkrtz(p[8+2*e], p[9+2*e]);
      A1.u[e] = cv.u;
    }

    // ds_read V frags (swizzled)
    f16x8 vc00 = *(const f16x8*)(sV[cur] + rdV00);
    f16x8 vc01 = *(const f16x8*)(sV[cur] + rdV01);
    f16x8 vc10 = *(const f16x8*)(sV[cur] + rdV10);
    f16x8 vc11 = *(const f16x8*)(sV[cur] + rdV11);
    f16x8 vc20 = *(const f16x8*)(sV[cur] + rdV20);
    f16x8 vc21 = *(const f16x8*)(sV[cur] + rdV21);

    acc0 = __builtin_amdgcn_mfma_f32_32x32x16_f16(A0.v, vc00, acc0, 0,0,0);
    acc0 = __builtin_amdgcn_mfma_f32_32x32x16_f16(A1.v, vc01, acc0, 0,0,0);
    acc1 = __builtin_amdgcn_mfma_f32_32x32x16_f16(A0.v, vc10, acc1, 0,0,0);
    acc1 = __builtin_amdgcn_mfma_f32_32x32x16_f16(A1.v, vc11, acc1, 0,0,0);
    acc2 = __builtin_amdgcn_mfma_f32_32x32x16_f16(A0.v, vc20, acc2, 0,0,0);
    acc2 = __builtin_amdgcn_mfma_f32_32x32x16_f16(A1.v, vc21, acc2, 0,0,0);

    // ds_write staged tile t+1 (other buffer)
    if (t+1 < ntiles) {
      int nxt = (t+1) & 1;
      {
        int gid = w*64 + l;
        *(float4*)(sK[nxt] + ((gid>>3)*128 + (((gid&7)^((gid>>3)&7))<<4))) = stg0;
      }
      {
        int gid = w*64 + l;
        *(float4*)(sV[nxt] + ((gid>>2)*64 + (((gid&3)^((gid>>3)&3))<<4))) = stg1;
      }
      if (i2 == 8) {
        int gid = 4*64 + l;
        *(float4*)(sV[nxt] + ((gid>>2)*64 + (((gid&3)^((gid>>3)&3))<<4))) = stg2;
      }
    }
    __syncthreads();
  }

  // merge per-half lsum partials
  lsum += __shfl_xor(lsum, 32);

  // epilogue: write raw per-wave partials
  int pidx = (b*128 + qtile)*nsplit + z;
  if (hf==0) {
    wsM[pidx*32 + ln] = m;
    wsL[pidx*32 + ln] = lsum;
  }
  float* po = wsO + (size_t)pidx*32*80;
  #pragma unroll
  for (int r=0;r<16;r++) {
    int row = (r&3) + 8*(r>>2) + 4*hf;
    po[row*80 + ln]      = acc0[r];
    po[row*80 + 32 + ln] = acc1[r];
    if (ln < 16) po[row*80 + 64 + ln] = acc2[r];
  }
}

// --------------------------------------------------------------------------
// K3b: merge nsplit key-splits + wo-projection + residual into h.
// --------------------------------------------------------------------------
__global__ __launch_bounds__(256) void k_merge_proj(
    const float* __restrict__ wsO, const float* __restrict__ wsM,
    const float* __restrict__ wsL, const float* __restrict__ wo,
    float* __restrict__ h, int nsplit)
{
  int tid = threadIdx.x;
  int c   = tid & 15;
  int token = blockIdx.x*16 + (tid>>4);
  int qrow = token & 31;
  int qt   = token >> 5;              // global q-tile (0..511)
  int base = qt*nsplit;
  float M = -1e30f;
  for (int s=0; s<nsplit; ++s) M = fmaxf(M, wsM[(base+s)*32 + qrow]);
  float wgt[8];
  float L = 0.f;
  for (int s=0; s<nsplit; ++s) {
    wgt[s] = exp2f(wsM[(base+s)*32 + qrow] - M);
    L += wgt[s]*wsL[(base+s)*32 + qrow];
  }
  float invL = 1.f/L;
  float att[5];
  #pragma unroll
  for (int i=0;i<5;i++) {
    float a = 0.f;
    for (int s=0; s<nsplit; ++s)
      a += wgt[s]*wsO[((size_t)(base+s)*32 + qrow)*80 + i*16 + c];
    att[i] = a*invL;
  }
  int g = GRADE16[c];
  float* ht = h + (size_t)token*80;
  #pragma unroll
  for (int o=0;o<5;o++) {
    const float* wor = wo + g*25 + o*5;
    float a = 0.f;
    #pragma unroll
    for (int i=0;i<5;i++) a += att[i]*wor[i];
    ht[o*16 + c] += a;
  }
}

// --------------------------------------------------------------------------
// K4: fused equi_layernorm + MLP + residual.
// --------------------------------------------------------------------------
__global__ __launch_bounds__(256) void k_mlp(
    float* __restrict__ h,
    const float* __restrict__ w1, const float* __restrict__ w2)
{
  __shared__ float sh1[16][10][16];
  int tid = threadIdx.x;
  int c   = tid & 15;
  int tl  = tid >> 4;
  int token = blockIdx.x*16 + tl;
  float* ht = h + (size_t)token*80;
  float hv[5];
  #pragma unroll
  for (int i=0;i<5;i++) hv[i] = ht[i*16 + c];
  bool inner = (0x469D >> c) & 1;
  float part = 0.f;
  if (inner) {
    #pragma unroll
    for (int i=0;i<5;i++) part += hv[i]*hv[i];
  }
  part += __shfl_xor(part, 1);
  part += __shfl_xor(part, 2);
  part += __shfl_xor(part, 4);
  part += __shfl_xor(part, 8);
  float denom = sqrtf(part*(1.f/80.f) + 1e-6f);
  float rinv = 1.f/denom;
  float rln[5];
  #pragma unroll
  for (int i=0;i<5;i++) rln[i] = hv[i]*rinv;

  int g = GRADE16[c];
  #pragma unroll
  for (int o=0;o<10;o++) {
    const float* w1r = w1 + g*50 + o*5;
    float a=0.f;
    #pragma unroll
    for (int i=0;i<5;i++) a += rln[i]*w1r[i];
    sh1[tl][o][c] = a;
  }
  __syncthreads();
  float gpv[5];
  #pragma unroll
  for (int hh=0; hh<5; hh++) {
    float a = 0.f;
    int n = GPT.cnt[c];
    for (int e=0; e<n; ++e) {
      a += GPT.ss[c][e]*sh1[tl][hh][GPT.ii[c][e]]*sh1[tl][5+hh][GPT.jj[c][e]];
    }
    gpv[hh] = a;
  }
  int base = (tid & 63) & ~15;
  #pragma unroll
  for (int hh=0;hh<5;hh++) {
    float g0 = __shfl(gpv[hh], base);
    float u  = 0.7978845608028654f*(g0 + 0.044715f*g0*g0*g0);
    float gate = 0.5f*g0*(1.f + tanhf(u));
    gpv[hh] *= gate;
  }
  #pragma unroll
  for (int o=0;o<5;o++) {
    const float* w2r = w2 + g*25 + o*5;
    float a=0.f;
    #pragma unroll
    for (int i=0;i<5;i++) a += gpv[i]*w2r[i];
    ht[o*16+c] += a;
  }
}

// --------------------------------------------------------------------------
// K5: final equi_linear (w_out) + output extraction.
// --------------------------------------------------------------------------
__global__ __launch_bounds__(256) void k_out(
    const float* __restrict__ h, const float* __restrict__ w_out,
    float* __restrict__ out)
{
  int gid = blockIdx.x*256 + threadIdx.x;
  if (gid >= NTOK*35) return;
  int j = gid % 35, token = gid / 35;
  const float* ht = h + (size_t)token*80;
  float a = 0.f;
  if (j < 32) {
    const float* w = w_out + j*5;              // grade 0, row j
    #pragma unroll
    for (int i=0;i<5;i++) a += ht[i*16 + 0]*w[i];
  } else {
    int c = (j==32)?5:((j==33)?6:8);
    const float* w = w_out + 2*160 + 0*5;      // grade 2, row 0
    #pragma unroll
    for (int i=0;i<5;i++) a += ht[i*16 + c]*w[i];
  }
  out[gid] = a;
}

// --------------------------------------------------------------------------
extern "C" void kernel_launch(void* const* d_in, const int* in_sizes, int n_in,
                              void* d_out, int out_size, void* d_ws, size_t ws_size,
                              hipStream_t stream) {
  const float* x     = (const float*)d_in[0];
  const float* w_in  = (const float*)d_in[1];
  const float* w_out = (const float*)d_in[2];
  const float* wq    = (const float*)d_in[3];
  const float* wk    = (const float*)d_in[4];
  const float* wv    = (const float*)d_in[5];
  const float* wo    = (const float*)d_in[6];
  const float* w1    = (const float*)d_in[7];
  const float* w2    = (const float*)d_in[8];
  float* out = (float*)d_out;

  // carve: h fp32 + qf,kf fp16[64/row] + vf fp16 tiled + nsplit partials
  char* p = (char*)d_ws;
  float* h = (float*)p;              p += (size_t)NTOK*80*4;
  _Float16* qf = (_Float16*)p;       p += (size_t)NTOK*QP*2;
  _Float16* kf = (_Float16*)p;       p += (size_t)NTOK*QP*2;
  _Float16* vf = (_Float16*)p;       p += (size_t)NB*128*VTROWS*32*2;
  size_t fixed = (size_t)((char*)p - (char*)d_ws);
  int nsplit = 4;    // R18: best measured tradeoff (R16 occupancy, R17 swizzle)
  if (fixed + (size_t)512*4*32*(80+2)*4 > ws_size) nsplit = 2;
  float* wsO = (float*)p;            p += (size_t)512*nsplit*32*80*4;
  float* wsM = (float*)p;            p += (size_t)512*nsplit*32*4;
  float* wsL = (float*)p;

  k_init_h<<<(NTOK*5 + 255)/256, 256, 0, stream>>>(x, w_in, h);
  for (int blk=0; blk<3; ++blk) {
    k_ln_qkv<<<NTOK/16, 256, 0, stream>>>(h, wq+blk*125, wk+blk*125, wv+blk*125,
                                          qf, kf, vf);
    k_attn_lds<<<128*nsplit, 256, 0, stream>>>(qf, kf, vf, wsO, wsM, wsL, nsplit);
    k_merge_proj<<<NTOK/16, 256, 0, stream>>>(wsO, wsM, wsL, wo+blk*125, h, nsplit);
    k_mlp<<<NTOK/16, 256, 0, stream>>>(h, w1+blk*250, w2+blk*125);
  }
  k_out<<<(NTOK*35 + 255)/256, 256, 0, stream>>>(h, w_out, out);
}

// Round 19
// 231.388 us; speedup vs baseline: 1.1087x; 1.0457x over previous
//
#include <hip/hip_runtime.h>
#include <hip/hip_bf16.h>
#include <math.h>

typedef __attribute__((ext_vector_type(8)))  _Float16 f16x8;
typedef __attribute__((ext_vector_type(2)))  __fp16   fp16v2;
typedef __attribute__((ext_vector_type(16))) float    f32x16;

// ---------------------------------------------------------------------------
// GATr forward on MI355X. B=4, N=4096, H=5, BLK=3, INV=32, 16 blades.
// R19: R18 attention (LDS-staged K/V, nsplit=4, V slot-swizzle) + FUSED
// merge+wo-proj+LN+MLP kernel (one launch, h kept in registers between
// attention epilogue and MLP -> one h round-trip saved per block).
// ---------------------------------------------------------------------------

namespace ga {
constexpr int MASKS[16] = {0,1,2,4,8,3,5,6,9,10,12,7,11,13,14,15};
constexpr int popc4(int x){ return (x&1)+((x>>1)&1)+((x>>2)&1)+((x>>3)&1); }
constexpr int idx_of(int m){ int r=-1; for(int i=0;i<16;i++) if(MASKS[i]==m) r=i; return r; }
struct GPTab {
  int cnt[16];
  signed char ii[16][16];
  signed char jj[16][16];
  float ss[16][16];
};
constexpr GPTab make_gptab(){
  GPTab t{};
  for(int i=0;i<16;i++) for(int j=0;j<16;j++){
    int a=MASKS[i], b=MASKS[j];
    if((a&b&1)!=0) continue;           // e0^2 = 0 kills the term
    int sw=0;
    for(int bi=0;bi<4;bi++) if((b>>bi)&1) sw += popc4(a>>(bi+1));
    int k = idx_of(a^b);
    int c = t.cnt[k];
    t.ii[k][c]=(signed char)i; t.jj[k][c]=(signed char)j;
    t.ss[k][c]=(sw&1)? -1.0f : 1.0f;
    t.cnt[k]=c+1;
  }
  return t;
}
} // namespace ga

__device__ const ga::GPTab GPT = ga::make_gptab();
__constant__ int GRADE16[16] = {0,1,1,1,1,2,2,2,2,2,2,3,3,3,3,4};
__constant__ int CPOS16[16] = {0,-1,1,2,3,-1,-1,4,-1,5,6,-1,-1,-1,7,-1};

#define NTOK 16384   // B*N
#define NSEQ 4096
#define NB 4
#define QP 64        // q/k row stride (40 real feats + pads; 128B rows)
#define VTROWS 80    // v tile rows (feats)
#define THR2 11.54f  // defer-max threshold in log2 domain (= 8 nats)

// --------------------------------------------------------------------------
// K1: h[token][o][c] = equi_linear(mv, w_in); mv sparse.
// --------------------------------------------------------------------------
__global__ __launch_bounds__(256) void k_init_h(
    const float* __restrict__ x, const float* __restrict__ w_in,
    float* __restrict__ h)
{
  int gid = blockIdx.x*256 + threadIdx.x;      // token*5 + o
  if (gid >= NTOK*5) return;
  int o = gid % 5, token = gid / 5;
  const float* xt = x + (size_t)token*35;
  const float* w0 = w_in + o*32;               // grade-0 block, row o
  float s = w0[0];                             // mv[0][0] = 1.0
  #pragma unroll
  for (int i=1;i<32;i++) s += w0[i]*xt[i];
  float w2c = w_in[2*160 + o*32 + 0];          // grade-2, input channel 0
  float* ht = h + (size_t)token*80 + o*16;
  #pragma unroll
  for (int c=0;c<16;c++) ht[c] = 0.f;
  ht[0] = s;
  ht[5] = w2c*xt[32];
  ht[6] = w2c*xt[33];
  ht[8] = w2c*xt[34];
}

// --------------------------------------------------------------------------
// K2: fused equi_layernorm + q,k,v equi_linear -> fp16 staging.
// q/k: [token][64]; q pre-scaled by scale*log2(e).
// v: TILE-MAJOR vt[b][tile][feat(80)][col], key->col permuted (pi).
// --------------------------------------------------------------------------
__global__ __launch_bounds__(256) void k_ln_qkv(
    const float* __restrict__ h,
    const float* __restrict__ wq, const float* __restrict__ wk,
    const float* __restrict__ wv,
    _Float16* __restrict__ qf, _Float16* __restrict__ kf,
    _Float16* __restrict__ vf)
{
  int tid = threadIdx.x;
  int c   = tid & 15;
  int token = blockIdx.x*16 + (tid>>4);
  int b = token >> 12;          // /4096
  int n = token & 4095;
  int vt_tile = b*128 + (n>>5);
  int nn = n & 31;
  int t  = (nn>>2)&3;
  int t2 = ((t<<1)|(t>>1))&3;             // 0,3 fixed; 1<->2
  int vt_col = (nn&3) | (t2<<2) | (nn&16);
  const float* ht = h + (size_t)token*80;
  float hv[5];
  #pragma unroll
  for (int i=0;i<5;i++) hv[i] = ht[i*16 + c];
  bool inner = (0x469D >> c) & 1;
  float part = 0.f;
  if (inner) {
    #pragma unroll
    for (int i=0;i<5;i++) part += hv[i]*hv[i];
  }
  part += __shfl_xor(part, 1);
  part += __shfl_xor(part, 2);
  part += __shfl_xor(part, 4);
  part += __shfl_xor(part, 8);
  float denom = sqrtf(part*(1.f/80.f) + 1e-6f);
  float rinv = 1.f/denom;
  float rln[5];
  #pragma unroll
  for (int i=0;i<5;i++) rln[i] = hv[i]*rinv;

  int g = GRADE16[c];
  int cp = CPOS16[c];
  const float scaleq = 0.16129820906f;   // (1/sqrt(80)) * log2(e)
  #pragma unroll
  for (int o=0;o<5;o++) {
    const float* wqr = wq + g*25 + o*5;
    const float* wkr = wk + g*25 + o*5;
    const float* wvr = wv + g*25 + o*5;
    float aq=0.f, ak=0.f, av=0.f;
    #pragma unroll
    for (int i=0;i<5;i++) {
      aq += rln[i]*wqr[i];
      ak += rln[i]*wkr[i];
      av += rln[i]*wvr[i];
    }
    vf[((size_t)vt_tile*VTROWS + o*16 + c)*32 + vt_col] = (_Float16)av;
    if (inner) {
      size_t qo = (size_t)token*QP + o*8 + cp;
      qf[qo] = (_Float16)(aq*scaleq);
      kf[qo] = (_Float16)ak;
    }
  }
  if (c < 8) {
    size_t po = (size_t)token*QP + 40 + c;
    qf[po] = (_Float16)0.f;
    kf[po] = (_Float16)0.f;
  }
}

// --------------------------------------------------------------------------
// K3: LDS-staged flash attention (R18: R16 structure + R17 V slot-swizzle).
// Block = 256 thr = 4 waves; each wave owns a DIFFERENT 32-row Q-tile; all
// share the SAME key range. K (4KB) + V (5KB) per tile staged once per
// block, double-buffered, 1 barrier/tile. Swapped QK^T; pi-permuted V.
// V store slot = d ^ ((row>>1)&3)  (4-way-minimal bank spread).
// Epilogue: raw per-wave partials (O, m, l) -> fused merge+MLP kernel.
// --------------------------------------------------------------------------
__global__ __launch_bounds__(256, 2) void k_attn_lds(
    const _Float16* __restrict__ qf, const _Float16* __restrict__ kf,
    const _Float16* __restrict__ vf,
    float* __restrict__ wsO, float* __restrict__ wsM,
    float* __restrict__ wsL, int nsplit)
{
  __shared__ __align__(16) char sK[2][4096];
  __shared__ __align__(16) char sV[2][5120];
  __shared__ __align__(16) float sF[4][32];
  int tid = threadIdx.x;
  int w  = tid >> 6;
  int l  = tid & 63;
  int ln = l & 31;
  int hf = l >> 5;
  int bid = blockIdx.x;
  int xcd = bid & 7;
  int b   = xcd & 3;
  int rest = bid >> 3;
  int qlo  = rest & 15;                   // 16 q-lo groups
  int z    = rest >> 4;                   // 0..nsplit-1
  int qgroup = (xcd>>2)*16 + qlo;         // 0..31
  int qtile = qgroup*4 + w;               // 0..127 (per batch)
  int rowbase = b*NSEQ + qtile*32;
  int ntiles = (NSEQ/nsplit) >> 5;
  int kbeg = z*(NSEQ/nsplit);

  // Q frags (B operand): j=lane&31=qrow, k=(lane>>5)*8+e
  const _Float16* qp = qf + (size_t)(rowbase + ln)*QP + hf*8;
  f16x8 q0 = *(const f16x8*)(qp);
  f16x8 q1 = *(const f16x8*)(qp + 16);
  f16x8 q2 = *(const f16x8*)(qp + 32);

  f32x16 acc0, acc1, acc2;
  #pragma unroll
  for (int r=0;r<16;r++){ acc0[r]=0.f; acc1[r]=0.f; acc2[r]=0.f; }
  float m = -1e30f, lsum = 0.f;

  // swizzled ds_read byte offsets (fixed per lane)
  int rdK0 = ln*128 + (((0+hf)^(ln&7))<<4);
  int rdK1 = ln*128 + (((2+hf)^(ln&7))<<4);
  int rdK2 = ln*128 + (((4+hf)^(ln&7))<<4);
  int vr0 = ln, vr1 = 32+ln, vr2 = 64+(ln&15);
  int sw0 = (vr0>>1)&3, sw1 = (vr1>>1)&3, sw2 = (vr2>>1)&3;
  int rdV00 = vr0*64 + (((hf  )^sw0)<<4);
  int rdV01 = vr0*64 + (((hf+2)^sw0)<<4);
  int rdV10 = vr1*64 + (((hf  )^sw1)<<4);
  int rdV11 = vr1*64 + (((hf+2)^sw1)<<4);
  int rdV20 = vr2*64 + (((hf  )^sw2)<<4);
  int rdV21 = vr2*64 + (((hf+2)^sw2)<<4);

  const _Float16* kfb = kf + (size_t)b*NSEQ*QP;
  const _Float16* vfb = vf + (size_t)(b*128)*(VTROWS*32);

  // ---- prologue: stage tile 0 into buf 0 ----
  {
    const float4* kT = (const float4*)(kfb + (size_t)kbeg*QP);
    const float4* vT = (const float4*)(vfb + (size_t)(kbeg>>5)*(VTROWS*32));
    #pragma unroll
    for (int i=w; i<9; i+=4) {
      float4 d = (i<4) ? kT[i*64 + l] : vT[(i-4)*64 + l];
      if (i<4) {
        int gid = i*64 + l;
        *(float4*)(sK[0] + ((gid>>3)*128 + (((gid&7)^((gid>>3)&7))<<4))) = d;
      } else {
        int gid = (i-4)*64 + l;
        *(float4*)(sV[0] + ((gid>>2)*64 + (((gid&3)^((gid>>3)&3))<<4))) = d;
      }
    }
  }
  __syncthreads();

  for (int t=0; t<ntiles; ++t) {
    int cur = t & 1;
    // issue global loads for tile t+1 (into regs; written to LDS later)
    float4 stg0, stg1, stg2; int i2=-1;
    if (t+1 < ntiles) {
      int koffn = kbeg + (t+1)*32;
      const float4* kT = (const float4*)(kfb + (size_t)koffn*QP);
      const float4* vT = (const float4*)(vfb + (size_t)(koffn>>5)*(VTROWS*32));
      stg0 = kT[w*64+l];
      stg1 = vT[w*64+l];
      if (w==0) { i2 = 8; stg2 = vT[4*64+l]; }
    }

    // ds_read K frags (swizzled)
    f16x8 kc0 = *(const f16x8*)(sK[cur] + rdK0);
    f16x8 kc1 = *(const f16x8*)(sK[cur] + rdK1);
    f16x8 kc2 = *(const f16x8*)(sK[cur] + rdK2);

    // QK^T
    f32x16 S;
    #pragma unroll
    for (int r=0;r<16;r++) S[r]=0.f;
    S = __builtin_amdgcn_mfma_f32_32x32x16_f16(kc0, q0, S, 0,0,0);
    S = __builtin_amdgcn_mfma_f32_32x32x16_f16(kc1, q1, S, 0,0,0);
    S = __builtin_amdgcn_mfma_f32_32x32x16_f16(kc2, q2, S, 0,0,0);

    // tile max: balanced tree
    float t01 = fmaxf(S[0],S[1]),   t23 = fmaxf(S[2],S[3]);
    float t45 = fmaxf(S[4],S[5]),   t67 = fmaxf(S[6],S[7]);
    float t89 = fmaxf(S[8],S[9]),   tab = fmaxf(S[10],S[11]);
    float tcd = fmaxf(S[12],S[13]), tef = fmaxf(S[14],S[15]);
    float u0 = fmaxf(t01,t23), u1 = fmaxf(t45,t67);
    float u2 = fmaxf(t89,tab), u3 = fmaxf(tcd,tef);
    float tmax = fmaxf(fmaxf(u0,u1), fmaxf(u2,u3));
    tmax = fmaxf(tmax, __shfl_xor(tmax, 32));
    if (!__all(tmax <= m + THR2)) {
      float mn = fmaxf(m, tmax);
      float f = exp2f(m - mn);
      lsum *= f;
      m = mn;
      if (hf==0) sF[w][ln] = f;
      float fv[16];
      *(float4*)&fv[0]  = *(const float4*)&sF[w][ 0 + hf*4];
      *(float4*)&fv[4]  = *(const float4*)&sF[w][ 8 + hf*4];
      *(float4*)&fv[8]  = *(const float4*)&sF[w][16 + hf*4];
      *(float4*)&fv[12] = *(const float4*)&sF[w][24 + hf*4];
      #pragma unroll
      for (int r=0;r<16;r++){ float fr=fv[r]; acc0[r]*=fr; acc1[r]*=fr; acc2[r]*=fr; }
    }
    float p[16];
    #pragma unroll
    for (int r=0;r<16;r++) p[r] = exp2f(S[r] - m);
    float s0 = (p[0]+p[1]) + (p[2]+p[3]);
    float s1 = (p[4]+p[5]) + (p[6]+p[7]);
    float s2 = (p[8]+p[9]) + (p[10]+p[11]);
    float s3 = (p[12]+p[13]) + (p[14]+p[15]);
    lsum += (s0+s1) + (s2+s3);

    // pack P -> fp16 A-frags: LOCAL pack (pi-permuted V cols)
    union { unsigned u[4]; f16x8 v; } A0, A1;
    #pragma unroll
    for (int e=0;e<4;e++) {
      union { fp16v2 h2; unsigned u; } cv;
      cv.h2 = __builtin_amdgcn_cvt_pkrtz(p[2*e], p[2*e+1]);
      A0.u[e] = cv.u;
    }
    #pragma unroll
    for (int e=0;e<4;e++) {
      union { fp16v2 h2; unsigned u; } cv;
      cv.h2 = __builtin_amdgcn_cvt_pkrtz(p[8+2*e], p[9+2*e]);
      A1.u[e] = cv.u;
    }

    // ds_read V frags (swizzled)
    f16x8 vc00 = *(const f16x8*)(sV[cur] + rdV00);
    f16x8 vc01 = *(const f16x8*)(sV[cur] + rdV01);
    f16x8 vc10 = *(const f16x8*)(sV[cur] + rdV10);
    f16x8 vc11 = *(const f16x8*)(sV[cur] + rdV11);
    f16x8 vc20 = *(const f16x8*)(sV[cur] + rdV20);
    f16x8 vc21 = *(const f16x8*)(sV[cur] + rdV21);

    acc0 = __builtin_amdgcn_mfma_f32_32x32x16_f16(A0.v, vc00, acc0, 0,0,0);
    acc0 = __builtin_amdgcn_mfma_f32_32x32x16_f16(A1.v, vc01, acc0, 0,0,0);
    acc1 = __builtin_amdgcn_mfma_f32_32x32x16_f16(A0.v, vc10, acc1, 0,0,0);
    acc1 = __builtin_amdgcn_mfma_f32_32x32x16_f16(A1.v, vc11, acc1, 0,0,0);
    acc2 = __builtin_amdgcn_mfma_f32_32x32x16_f16(A0.v, vc20, acc2, 0,0,0);
    acc2 = __builtin_amdgcn_mfma_f32_32x32x16_f16(A1.v, vc21, acc2, 0,0,0);

    // ds_write staged tile t+1 (other buffer)
    if (t+1 < ntiles) {
      int nxt = (t+1) & 1;
      {
        int gid = w*64 + l;
        *(float4*)(sK[nxt] + ((gid>>3)*128 + (((gid&7)^((gid>>3)&7))<<4))) = stg0;
      }
      {
        int gid = w*64 + l;
        *(float4*)(sV[nxt] + ((gid>>2)*64 + (((gid&3)^((gid>>3)&3))<<4))) = stg1;
      }
      if (i2 == 8) {
        int gid = 4*64 + l;
        *(float4*)(sV[nxt] + ((gid>>2)*64 + (((gid&3)^((gid>>3)&3))<<4))) = stg2;
      }
    }
    __syncthreads();
  }

  // merge per-half lsum partials
  lsum += __shfl_xor(lsum, 32);

  // epilogue: write raw per-wave partials
  int pidx = (b*128 + qtile)*nsplit + z;
  if (hf==0) {
    wsM[pidx*32 + ln] = m;
    wsL[pidx*32 + ln] = lsum;
  }
  float* po = wsO + (size_t)pidx*32*80;
  #pragma unroll
  for (int r=0;r<16;r++) {
    int row = (r&3) + 8*(r>>2) + 4*hf;
    po[row*80 + ln]      = acc0[r];
    po[row*80 + 32 + ln] = acc1[r];
    if (ln < 16) po[row*80 + 64 + ln] = acc2[r];
  }
}

// --------------------------------------------------------------------------
// K4 (FUSED): merge nsplit key-splits + wo-proj + residual + equi_layernorm
// + MLP (w1 -> geometric product -> gated gelu -> w2) + residual.
// h is read once and written once; post-attention h lives in registers.
// 16 threads/token (one per blade), 16 tokens/block.
// --------------------------------------------------------------------------
__global__ __launch_bounds__(256) void k_merge_mlp(
    const float* __restrict__ wsO, const float* __restrict__ wsM,
    const float* __restrict__ wsL, const float* __restrict__ wo,
    const float* __restrict__ w1, const float* __restrict__ w2,
    float* __restrict__ h, int nsplit)
{
  __shared__ float sh1[16][10][16];
  int tid = threadIdx.x;
  int c   = tid & 15;
  int tl  = tid >> 4;
  int token = blockIdx.x*16 + tl;
  int qrow = token & 31;
  int qt   = token >> 5;              // global q-tile (0..511)
  int g = GRADE16[c];
  float* ht = h + (size_t)token*80;

  // ---- merge attention partials ----
  int base = qt*nsplit;
  float M = -1e30f;
  for (int s=0; s<nsplit; ++s) M = fmaxf(M, wsM[(base+s)*32 + qrow]);
  float wgt[8];
  float L = 0.f;
  for (int s=0; s<nsplit; ++s) {
    wgt[s] = exp2f(wsM[(base+s)*32 + qrow] - M);
    L += wgt[s]*wsL[(base+s)*32 + qrow];
  }
  float invL = 1.f/L;
  float att[5];
  #pragma unroll
  for (int i=0;i<5;i++) {
    float a = 0.f;
    for (int s=0; s<nsplit; ++s)
      a += wgt[s]*wsO[((size_t)(base+s)*32 + qrow)*80 + i*16 + c];
    att[i] = a*invL;
  }

  // ---- wo-projection + residual: post-attention h in registers ----
  float hv[5];
  #pragma unroll
  for (int o=0;o<5;o++) {
    const float* wor = wo + g*25 + o*5;
    float a = 0.f;
    #pragma unroll
    for (int i=0;i<5;i++) a += att[i]*wor[i];
    hv[o] = ht[o*16 + c] + a;
  }

  // ---- equi_layernorm on hv ----
  bool inner = (0x469D >> c) & 1;
  float part = 0.f;
  if (inner) {
    #pragma unroll
    for (int i=0;i<5;i++) part += hv[i]*hv[i];
  }
  part += __shfl_xor(part, 1);
  part += __shfl_xor(part, 2);
  part += __shfl_xor(part, 4);
  part += __shfl_xor(part, 8);
  float denom = sqrtf(part*(1.f/80.f) + 1e-6f);
  float rinv = 1.f/denom;
  float rln[5];
  #pragma unroll
  for (int i=0;i<5;i++) rln[i] = hv[i]*rinv;

  // ---- MLP: w1 -> GP -> gated gelu -> w2 ----
  #pragma unroll
  for (int o=0;o<10;o++) {
    const float* w1r = w1 + g*50 + o*5;
    float a=0.f;
    #pragma unroll
    for (int i=0;i<5;i++) a += rln[i]*w1r[i];
    sh1[tl][o][c] = a;
  }
  __syncthreads();
  float gpv[5];
  #pragma unroll
  for (int hh=0; hh<5; hh++) {
    float a = 0.f;
    int n = GPT.cnt[c];
    for (int e=0; e<n; ++e) {
      a += GPT.ss[c][e]*sh1[tl][hh][GPT.ii[c][e]]*sh1[tl][5+hh][GPT.jj[c][e]];
    }
    gpv[hh] = a;
  }
  int lbase = (tid & 63) & ~15;
  #pragma unroll
  for (int hh=0;hh<5;hh++) {
    float g0 = __shfl(gpv[hh], lbase);
    float u  = 0.7978845608028654f*(g0 + 0.044715f*g0*g0*g0);
    float gate = 0.5f*g0*(1.f + tanhf(u));
    gpv[hh] *= gate;
  }
  #pragma unroll
  for (int o=0;o<5;o++) {
    const float* w2r = w2 + g*25 + o*5;
    float a=0.f;
    #pragma unroll
    for (int i=0;i<5;i++) a += gpv[i]*w2r[i];
    ht[o*16+c] = hv[o] + a;
  }
}

// --------------------------------------------------------------------------
// K5: final equi_linear (w_out) + output extraction.
// --------------------------------------------------------------------------
__global__ __launch_bounds__(256) void k_out(
    const float* __restrict__ h, const float* __restrict__ w_out,
    float* __restrict__ out)
{
  int gid = blockIdx.x*256 + threadIdx.x;
  if (gid >= NTOK*35) return;
  int j = gid % 35, token = gid / 35;
  const float* ht = h + (size_t)token*80;
  float a = 0.f;
  if (j < 32) {
    const float* w = w_out + j*5;              // grade 0, row j
    #pragma unroll
    for (int i=0;i<5;i++) a += ht[i*16 + 0]*w[i];
  } else {
    int c = (j==32)?5:((j==33)?6:8);
    const float* w = w_out + 2*160 + 0*5;      // grade 2, row 0
    #pragma unroll
    for (int i=0;i<5;i++) a += ht[i*16 + c]*w[i];
  }
  out[gid] = a;
}

// --------------------------------------------------------------------------
extern "C" void kernel_launch(void* const* d_in, const int* in_sizes, int n_in,
                              void* d_out, int out_size, void* d_ws, size_t ws_size,
                              hipStream_t stream) {
  const float* x     = (const float*)d_in[0];
  const float* w_in  = (const float*)d_in[1];
  const float* w_out = (const float*)d_in[2];
  const float* wq    = (const float*)d_in[3];
  const float* wk    = (const float*)d_in[4];
  const float* wv    = (const float*)d_in[5];
  const float* wo    = (const float*)d_in[6];
  const float* w1    = (const float*)d_in[7];
  const float* w2    = (const float*)d_in[8];
  float* out = (float*)d_out;

  // carve: h fp32 + qf,kf fp16[64/row] + vf fp16 tiled + nsplit partials
  char* p = (char*)d_ws;
  float* h = (float*)p;              p += (size_t)NTOK*80*4;
  _Float16* qf = (_Float16*)p;       p += (size_t)NTOK*QP*2;
  _Float16* kf = (_Float16*)p;       p += (size_t)NTOK*QP*2;
  _Float16* vf = (_Float16*)p;       p += (size_t)NB*128*VTROWS*32*2;
  size_t fixed = (size_t)((char*)p - (char*)d_ws);
  int nsplit = 4;    // R18-proven best tradeoff
  if (fixed + (size_t)512*4*32*(80+2)*4 > ws_size) nsplit = 2;
  float* wsO = (float*)p;            p += (size_t)512*nsplit*32*80*4;
  float* wsM = (float*)p;            p += (size_t)512*nsplit*32*4;
  float* wsL = (float*)p;

  k_init_h<<<(NTOK*5 + 255)/256, 256, 0, stream>>>(x, w_in, h);
  for (int blk=0; blk<3; ++blk) {
    k_ln_qkv<<<NTOK/16, 256, 0, stream>>>(h, wq+blk*125, wk+blk*125, wv+blk*125,
                                          qf, kf, vf);
    k_attn_lds<<<128*nsplit, 256, 0, stream>>>(qf, kf, vf, wsO, wsM, wsL, nsplit);
    k_merge_mlp<<<NTOK/16, 256, 0, stream>>>(wsO, wsM, wsL, wo+blk*125,
                                             w1+blk*250, w2+blk*125, h, nsplit);
  }
  k_out<<<(NTOK*35 + 255)/256, 256, 0, stream>>>(h, w_out, out);
}

// Round 20
// 219.671 us; speedup vs baseline: 1.1678x; 1.0533x over previous
//
#include <hip/hip_runtime.h>
#include <hip/hip_bf16.h>
#include <math.h>

typedef __attribute__((ext_vector_type(8)))  _Float16 f16x8;
typedef __attribute__((ext_vector_type(2)))  __fp16   fp16v2;
typedef __attribute__((ext_vector_type(16))) float    f32x16;

// ---------------------------------------------------------------------------
// GATr forward on MI355X. B=4, N=4096, H=5, BLK=3, INV=32, 16 blades.
// R20: R18 attention (LDS-staged K/V, nsplit=4, V slot-swizzle) + fusion
// chain: k_init_qkv (init+LN+QKV), k_merge_mlp_qkv (merge+MLP+next-block
// LN+QKV), k_merge_mlp (last block), k_out. 8 launches total (was 11).
// ---------------------------------------------------------------------------

namespace ga {
constexpr int MASKS[16] = {0,1,2,4,8,3,5,6,9,10,12,7,11,13,14,15};
constexpr int popc4(int x){ return (x&1)+((x>>1)&1)+((x>>2)&1)+((x>>3)&1); }
constexpr int idx_of(int m){ int r=-1; for(int i=0;i<16;i++) if(MASKS[i]==m) r=i; return r; }
struct GPTab {
  int cnt[16];
  signed char ii[16][16];
  signed char jj[16][16];
  float ss[16][16];
};
constexpr GPTab make_gptab(){
  GPTab t{};
  for(int i=0;i<16;i++) for(int j=0;j<16;j++){
    int a=MASKS[i], b=MASKS[j];
    if((a&b&1)!=0) continue;           // e0^2 = 0 kills the term
    int sw=0;
    for(int bi=0;bi<4;bi++) if((b>>bi)&1) sw += popc4(a>>(bi+1));
    int k = idx_of(a^b);
    int c = t.cnt[k];
    t.ii[k][c]=(signed char)i; t.jj[k][c]=(signed char)j;
    t.ss[k][c]=(sw&1)? -1.0f : 1.0f;
    t.cnt[k]=c+1;
  }
  return t;
}
} // namespace ga

__device__ const ga::GPTab GPT = ga::make_gptab();
__constant__ int GRADE16[16] = {0,1,1,1,1,2,2,2,2,2,2,3,3,3,3,4};
__constant__ int CPOS16[16] = {0,-1,1,2,3,-1,-1,4,-1,5,6,-1,-1,-1,7,-1};

#define NTOK 16384   // B*N
#define NSEQ 4096
#define NB 4
#define QP 64        // q/k row stride (40 real feats + pads; 128B rows)
#define VTROWS 80    // v tile rows (feats)
#define THR2 11.54f  // defer-max threshold in log2 domain (= 8 nats)

// --------------------------------------------------------------------------
// Device helper: LN + QKV staging from register h (hv[5] at blade c).
// --------------------------------------------------------------------------
__device__ __forceinline__ void ln_qkv_from_regs(
    const float hv[5], int c, int token,
    const float* __restrict__ wq, const float* __restrict__ wk,
    const float* __restrict__ wv,
    _Float16* __restrict__ qf, _Float16* __restrict__ kf,
    _Float16* __restrict__ vf)
{
  int b = token >> 12;
  int n = token & 4095;
  int vt_tile = b*128 + (n>>5);
  int nn = n & 31;
  int t  = (nn>>2)&3;
  int t2 = ((t<<1)|(t>>1))&3;             // pi: 0,3 fixed; 1<->2
  int vt_col = (nn&3) | (t2<<2) | (nn&16);
  bool inner = (0x469D >> c) & 1;
  float part = 0.f;
  if (inner) {
    #pragma unroll
    for (int i=0;i<5;i++) part += hv[i]*hv[i];
  }
  part += __shfl_xor(part, 1);
  part += __shfl_xor(part, 2);
  part += __shfl_xor(part, 4);
  part += __shfl_xor(part, 8);
  float rinv = 1.f/sqrtf(part*(1.f/80.f) + 1e-6f);
  float rln[5];
  #pragma unroll
  for (int i=0;i<5;i++) rln[i] = hv[i]*rinv;

  int g = GRADE16[c];
  int cp = CPOS16[c];
  const float scaleq = 0.16129820906f;   // (1/sqrt(80)) * log2(e)
  #pragma unroll
  for (int o=0;o<5;o++) {
    const float* wqr = wq + g*25 + o*5;
    const float* wkr = wk + g*25 + o*5;
    const float* wvr = wv + g*25 + o*5;
    float aq=0.f, ak=0.f, av=0.f;
    #pragma unroll
    for (int i=0;i<5;i++) {
      aq += rln[i]*wqr[i];
      ak += rln[i]*wkr[i];
      av += rln[i]*wvr[i];
    }
    vf[((size_t)vt_tile*VTROWS + o*16 + c)*32 + vt_col] = (_Float16)av;
    if (inner) {
      size_t qo = (size_t)token*QP + o*8 + cp;
      qf[qo] = (_Float16)(aq*scaleq);
      kf[qo] = (_Float16)ak;
    }
  }
  if (c < 8) {
    size_t po = (size_t)token*QP + 40 + c;
    qf[po] = (_Float16)0.f;
    kf[po] = (_Float16)0.f;
  }
}

// --------------------------------------------------------------------------
// K1 (FUSED): init h from x + LN + block-0 QKV staging.
// 16 threads/token; the 32-wide scalar dot is distributed across lanes.
// --------------------------------------------------------------------------
__global__ __launch_bounds__(256) void k_init_qkv(
    const float* __restrict__ x, const float* __restrict__ w_in,
    const float* __restrict__ wq, const float* __restrict__ wk,
    const float* __restrict__ wv,
    float* __restrict__ h, _Float16* __restrict__ qf,
    _Float16* __restrict__ kf, _Float16* __restrict__ vf)
{
  int tid = threadIdx.x;
  int c   = tid & 15;
  int token = blockIdx.x*16 + (tid>>4);
  const float* xt = x + (size_t)token*35;
  float* ht = h + (size_t)token*80;

  // distributed 32-dot: lane c covers j = c and c+16 (j=0: mv scalar = 1.0)
  float xa = (c==0) ? 1.f : xt[c];
  float xb = xt[c+16];
  float sv[5];
  #pragma unroll
  for (int o=0;o<5;o++) {
    const float* w0 = w_in + o*32;
    float partial = w0[c]*xa + w0[c+16]*xb;
    partial += __shfl_xor(partial,1);
    partial += __shfl_xor(partial,2);
    partial += __shfl_xor(partial,4);
    partial += __shfl_xor(partial,8);
    sv[o] = partial;
  }
  float hv[5];
  #pragma unroll
  for (int o=0;o<5;o++) {
    float w2c = w_in[2*160 + o*32];
    float v = 0.f;
    if (c==0) v = sv[o];
    else if (c==5) v = w2c*xt[32];
    else if (c==6) v = w2c*xt[33];
    else if (c==8) v = w2c*xt[34];
    hv[o] = v;
    ht[o*16+c] = v;
  }
  ln_qkv_from_regs(hv, c, token, wq, wk, wv, qf, kf, vf);
}

// --------------------------------------------------------------------------
// K3: LDS-staged flash attention (R18: R16 structure + R17 V slot-swizzle).
// Block = 256 thr = 4 waves; each wave owns a DIFFERENT 32-row Q-tile; all
// share the SAME key range. K (4KB) + V (5KB) per tile staged once per
// block, double-buffered, 1 barrier/tile. Swapped QK^T; pi-permuted V.
// V store slot = d ^ ((row>>1)&3). Epilogue: raw per-wave partials.
// --------------------------------------------------------------------------
__global__ __launch_bounds__(256, 2) void k_attn_lds(
    const _Float16* __restrict__ qf, const _Float16* __restrict__ kf,
    const _Float16* __restrict__ vf,
    float* __restrict__ wsO, float* __restrict__ wsM,
    float* __restrict__ wsL, int nsplit)
{
  __shared__ __align__(16) char sK[2][4096];
  __shared__ __align__(16) char sV[2][5120];
  __shared__ __align__(16) float sF[4][32];
  int tid = threadIdx.x;
  int w  = tid >> 6;
  int l  = tid & 63;
  int ln = l & 31;
  int hf = l >> 5;
  int bid = blockIdx.x;
  int xcd = bid & 7;
  int b   = xcd & 3;
  int rest = bid >> 3;
  int qlo  = rest & 15;
  int z    = rest >> 4;
  int qgroup = (xcd>>2)*16 + qlo;
  int qtile = qgroup*4 + w;
  int rowbase = b*NSEQ + qtile*32;
  int ntiles = (NSEQ/nsplit) >> 5;
  int kbeg = z*(NSEQ/nsplit);

  const _Float16* qp = qf + (size_t)(rowbase + ln)*QP + hf*8;
  f16x8 q0 = *(const f16x8*)(qp);
  f16x8 q1 = *(const f16x8*)(qp + 16);
  f16x8 q2 = *(const f16x8*)(qp + 32);

  f32x16 acc0, acc1, acc2;
  #pragma unroll
  for (int r=0;r<16;r++){ acc0[r]=0.f; acc1[r]=0.f; acc2[r]=0.f; }
  float m = -1e30f, lsum = 0.f;

  int rdK0 = ln*128 + (((0+hf)^(ln&7))<<4);
  int rdK1 = ln*128 + (((2+hf)^(ln&7))<<4);
  int rdK2 = ln*128 + (((4+hf)^(ln&7))<<4);
  int vr0 = ln, vr1 = 32+ln, vr2 = 64+(ln&15);
  int sw0 = (vr0>>1)&3, sw1 = (vr1>>1)&3, sw2 = (vr2>>1)&3;
  int rdV00 = vr0*64 + (((hf  )^sw0)<<4);
  int rdV01 = vr0*64 + (((hf+2)^sw0)<<4);
  int rdV10 = vr1*64 + (((hf  )^sw1)<<4);
  int rdV11 = vr1*64 + (((hf+2)^sw1)<<4);
  int rdV20 = vr2*64 + (((hf  )^sw2)<<4);
  int rdV21 = vr2*64 + (((hf+2)^sw2)<<4);

  const _Float16* kfb = kf + (size_t)b*NSEQ*QP;
  const _Float16* vfb = vf + (size_t)(b*128)*(VTROWS*32);

  {
    const float4* kT = (const float4*)(kfb + (size_t)kbeg*QP);
    const float4* vT = (const float4*)(vfb + (size_t)(kbeg>>5)*(VTROWS*32));
    #pragma unroll
    for (int i=w; i<9; i+=4) {
      float4 d = (i<4) ? kT[i*64 + l] : vT[(i-4)*64 + l];
      if (i<4) {
        int gid = i*64 + l;
        *(float4*)(sK[0] + ((gid>>3)*128 + (((gid&7)^((gid>>3)&7))<<4))) = d;
      } else {
        int gid = (i-4)*64 + l;
        *(float4*)(sV[0] + ((gid>>2)*64 + (((gid&3)^((gid>>3)&3))<<4))) = d;
      }
    }
  }
  __syncthreads();

  for (int t=0; t<ntiles; ++t) {
    int cur = t & 1;
    float4 stg0, stg1, stg2; int i2=-1;
    if (t+1 < ntiles) {
      int koffn = kbeg + (t+1)*32;
      const float4* kT = (const float4*)(kfb + (size_t)koffn*QP);
      const float4* vT = (const float4*)(vfb + (size_t)(koffn>>5)*(VTROWS*32));
      stg0 = kT[w*64+l];
      stg1 = vT[w*64+l];
      if (w==0) { i2 = 8; stg2 = vT[4*64+l]; }
    }

    f16x8 kc0 = *(const f16x8*)(sK[cur] + rdK0);
    f16x8 kc1 = *(const f16x8*)(sK[cur] + rdK1);
    f16x8 kc2 = *(const f16x8*)(sK[cur] + rdK2);

    f32x16 S;
    #pragma unroll
    for (int r=0;r<16;r++) S[r]=0.f;
    S = __builtin_amdgcn_mfma_f32_32x32x16_f16(kc0, q0, S, 0,0,0);
    S = __builtin_amdgcn_mfma_f32_32x32x16_f16(kc1, q1, S, 0,0,0);
    S = __builtin_amdgcn_mfma_f32_32x32x16_f16(kc2, q2, S, 0,0,0);

    float t01 = fmaxf(S[0],S[1]),   t23 = fmaxf(S[2],S[3]);
    float t45 = fmaxf(S[4],S[5]),   t67 = fmaxf(S[6],S[7]);
    float t89 = fmaxf(S[8],S[9]),   tab = fmaxf(S[10],S[11]);
    float tcd = fmaxf(S[12],S[13]), tef = fmaxf(S[14],S[15]);
    float u0 = fmaxf(t01,t23), u1 = fmaxf(t45,t67);
    float u2 = fmaxf(t89,tab), u3 = fmaxf(tcd,tef);
    float tmax = fmaxf(fmaxf(u0,u1), fmaxf(u2,u3));
    tmax = fmaxf(tmax, __shfl_xor(tmax, 32));
    if (!__all(tmax <= m + THR2)) {
      float mn = fmaxf(m, tmax);
      float f = exp2f(m - mn);
      lsum *= f;
      m = mn;
      if (hf==0) sF[w][ln] = f;
      float fv[16];
      *(float4*)&fv[0]  = *(const float4*)&sF[w][ 0 + hf*4];
      *(float4*)&fv[4]  = *(const float4*)&sF[w][ 8 + hf*4];
      *(float4*)&fv[8]  = *(const float4*)&sF[w][16 + hf*4];
      *(float4*)&fv[12] = *(const float4*)&sF[w][24 + hf*4];
      #pragma unroll
      for (int r=0;r<16;r++){ float fr=fv[r]; acc0[r]*=fr; acc1[r]*=fr; acc2[r]*=fr; }
    }
    float p[16];
    #pragma unroll
    for (int r=0;r<16;r++) p[r] = exp2f(S[r] - m);
    float s0 = (p[0]+p[1]) + (p[2]+p[3]);
    float s1 = (p[4]+p[5]) + (p[6]+p[7]);
    float s2 = (p[8]+p[9]) + (p[10]+p[11]);
    float s3 = (p[12]+p[13]) + (p[14]+p[15]);
    lsum += (s0+s1) + (s2+s3);

    union { unsigned u[4]; f16x8 v; } A0, A1;
    #pragma unroll
    for (int e=0;e<4;e++) {
      union { fp16v2 h2; unsigned u; } cv;
      cv.h2 = __builtin_amdgcn_cvt_pkrtz(p[2*e], p[2*e+1]);
      A0.u[e] = cv.u;
    }
    #pragma unroll
    for (int e=0;e<4;e++) {
      union { fp16v2 h2; unsigned u; } cv;
      cv.h2 = __builtin_amdgcn_cvt_pkrtz(p[8+2*e], p[9+2*e]);
      A1.u[e] = cv.u;
    }

    f16x8 vc00 = *(const f16x8*)(sV[cur] + rdV00);
    f16x8 vc01 = *(const f16x8*)(sV[cur] + rdV01);
    f16x8 vc10 = *(const f16x8*)(sV[cur] + rdV10);
    f16x8 vc11 = *(const f16x8*)(sV[cur] + rdV11);
    f16x8 vc20 = *(const f16x8*)(sV[cur] + rdV20);
    f16x8 vc21 = *(const f16x8*)(sV[cur] + rdV21);

    acc0 = __builtin_amdgcn_mfma_f32_32x32x16_f16(A0.v, vc00, acc0, 0,0,0);
    acc0 = __builtin_amdgcn_mfma_f32_32x32x16_f16(A1.v, vc01, acc0, 0,0,0);
    acc1 = __builtin_amdgcn_mfma_f32_32x32x16_f16(A0.v, vc10, acc1, 0,0,0);
    acc1 = __builtin_amdgcn_mfma_f32_32x32x16_f16(A1.v, vc11, acc1, 0,0,0);
    acc2 = __builtin_amdgcn_mfma_f32_32x32x16_f16(A0.v, vc20, acc2, 0,0,0);
    acc2 = __builtin_amdgcn_mfma_f32_32x32x16_f16(A1.v, vc21, acc2, 0,0,0);

    if (t+1 < ntiles) {
      int nxt = (t+1) & 1;
      {
        int gid = w*64 + l;
        *(float4*)(sK[nxt] + ((gid>>3)*128 + (((gid&7)^((gid>>3)&7))<<4))) = stg0;
      }
      {
        int gid = w*64 + l;
        *(float4*)(sV[nxt] + ((gid>>2)*64 + (((gid&3)^((gid>>3)&3))<<4))) = stg1;
      }
      if (i2 == 8) {
        int gid = 4*64 + l;
        *(float4*)(sV[nxt] + ((gid>>2)*64 + (((gid&3)^((gid>>3)&3))<<4))) = stg2;
      }
    }
    __syncthreads();
  }

  lsum += __shfl_xor(lsum, 32);

  int pidx = (b*128 + qtile)*nsplit + z;
  if (hf==0) {
    wsM[pidx*32 + ln] = m;
    wsL[pidx*32 + ln] = lsum;
  }
  float* po = wsO + (size_t)pidx*32*80;
  #pragma unroll
  for (int r=0;r<16;r++) {
    int row = (r&3) + 8*(r>>2) + 4*hf;
    po[row*80 + ln]      = acc0[r];
    po[row*80 + 32 + ln] = acc1[r];
    if (ln < 16) po[row*80 + 64 + ln] = acc2[r];
  }
}

// --------------------------------------------------------------------------
// Device helper: merge + wo-proj + residual + LN + MLP; returns new h in
// newh[5]; also needs sh1 LDS buffer.
// --------------------------------------------------------------------------
__device__ __forceinline__ void merge_mlp_body(
    const float* __restrict__ wsO, const float* __restrict__ wsM,
    const float* __restrict__ wsL, const float* __restrict__ wo,
    const float* __restrict__ w1, const float* __restrict__ w2,
    float* __restrict__ h, int nsplit,
    float (*sh1)[10][16], int tid, float newh[5])
{
  int c   = tid & 15;
  int tl  = tid >> 4;
  int token = blockIdx.x*16 + tl;
  int qrow = token & 31;
  int qt   = token >> 5;
  int g = GRADE16[c];
  float* ht = h + (size_t)token*80;

  int base = qt*nsplit;
  float M = -1e30f;
  for (int s=0; s<nsplit; ++s) M = fmaxf(M, wsM[(base+s)*32 + qrow]);
  float wgt[8];
  float L = 0.f;
  for (int s=0; s<nsplit; ++s) {
    wgt[s] = exp2f(wsM[(base+s)*32 + qrow] - M);
    L += wgt[s]*wsL[(base+s)*32 + qrow];
  }
  float invL = 1.f/L;
  float att[5];
  #pragma unroll
  for (int i=0;i<5;i++) {
    float a = 0.f;
    for (int s=0; s<nsplit; ++s)
      a += wgt[s]*wsO[((size_t)(base+s)*32 + qrow)*80 + i*16 + c];
    att[i] = a*invL;
  }

  float hv[5];
  #pragma unroll
  for (int o=0;o<5;o++) {
    const float* wor = wo + g*25 + o*5;
    float a = 0.f;
    #pragma unroll
    for (int i=0;i<5;i++) a += att[i]*wor[i];
    hv[o] = ht[o*16 + c] + a;
  }

  bool inner = (0x469D >> c) & 1;
  float part = 0.f;
  if (inner) {
    #pragma unroll
    for (int i=0;i<5;i++) part += hv[i]*hv[i];
  }
  part += __shfl_xor(part, 1);
  part += __shfl_xor(part, 2);
  part += __shfl_xor(part, 4);
  part += __shfl_xor(part, 8);
  float rinv = 1.f/sqrtf(part*(1.f/80.f) + 1e-6f);
  float rln[5];
  #pragma unroll
  for (int i=0;i<5;i++) rln[i] = hv[i]*rinv;

  #pragma unroll
  for (int o=0;o<10;o++) {
    const float* w1r = w1 + g*50 + o*5;
    float a=0.f;
    #pragma unroll
    for (int i=0;i<5;i++) a += rln[i]*w1r[i];
    sh1[tl][o][c] = a;
  }
  __syncthreads();
  float gpv[5];
  #pragma unroll
  for (int hh=0; hh<5; hh++) {
    float a = 0.f;
    int n = GPT.cnt[c];
    for (int e=0; e<n; ++e) {
      a += GPT.ss[c][e]*sh1[tl][hh][GPT.ii[c][e]]*sh1[tl][5+hh][GPT.jj[c][e]];
    }
    gpv[hh] = a;
  }
  int lbase = (tid & 63) & ~15;
  #pragma unroll
  for (int hh=0;hh<5;hh++) {
    float g0 = __shfl(gpv[hh], lbase);
    float u  = 0.7978845608028654f*(g0 + 0.044715f*g0*g0*g0);
    float gate = 0.5f*g0*(1.f + tanhf(u));
    gpv[hh] *= gate;
  }
  #pragma unroll
  for (int o=0;o<5;o++) {
    const float* w2r = w2 + g*25 + o*5;
    float a=0.f;
    #pragma unroll
    for (int i=0;i<5;i++) a += gpv[i]*w2r[i];
    newh[o] = hv[o] + a;
    ht[o*16+c] = newh[o];
  }
}

// --------------------------------------------------------------------------
// K4a (FUSED): merge+MLP + next-block LN+QKV staging.
// --------------------------------------------------------------------------
__global__ __launch_bounds__(256) void k_merge_mlp_qkv(
    const float* __restrict__ wsO, const float* __restrict__ wsM,
    const float* __restrict__ wsL, const float* __restrict__ wo,
    const float* __restrict__ w1, const float* __restrict__ w2,
    const float* __restrict__ wqn, const float* __restrict__ wkn,
    const float* __restrict__ wvn,
    float* __restrict__ h, _Float16* __restrict__ qf,
    _Float16* __restrict__ kf, _Float16* __restrict__ vf, int nsplit)
{
  __shared__ float sh1[16][10][16];
  int tid = threadIdx.x;
  float newh[5];
  merge_mlp_body(wsO, wsM, wsL, wo, w1, w2, h, nsplit, sh1, tid, newh);
  int c = tid & 15;
  int token = blockIdx.x*16 + (tid>>4);
  ln_qkv_from_regs(newh, c, token, wqn, wkn, wvn, qf, kf, vf);
}

// --------------------------------------------------------------------------
// K4b: merge+MLP only (last block).
// --------------------------------------------------------------------------
__global__ __launch_bounds__(256) void k_merge_mlp(
    const float* __restrict__ wsO, const float* __restrict__ wsM,
    const float* __restrict__ wsL, const float* __restrict__ wo,
    const float* __restrict__ w1, const float* __restrict__ w2,
    float* __restrict__ h, int nsplit)
{
  __shared__ float sh1[16][10][16];
  int tid = threadIdx.x;
  float newh[5];
  merge_mlp_body(wsO, wsM, wsL, wo, w1, w2, h, nsplit, sh1, tid, newh);
}

// --------------------------------------------------------------------------
// K5: final equi_linear (w_out) + output extraction.
// --------------------------------------------------------------------------
__global__ __launch_bounds__(256) void k_out(
    const float* __restrict__ h, const float* __restrict__ w_out,
    float* __restrict__ out)
{
  int gid = blockIdx.x*256 + threadIdx.x;
  if (gid >= NTOK*35) return;
  int j = gid % 35, token = gid / 35;
  const float* ht = h + (size_t)token*80;
  float a = 0.f;
  if (j < 32) {
    const float* w = w_out + j*5;              // grade 0, row j
    #pragma unroll
    for (int i=0;i<5;i++) a += ht[i*16 + 0]*w[i];
  } else {
    int c = (j==32)?5:((j==33)?6:8);
    const float* w = w_out + 2*160 + 0*5;      // grade 2, row 0
    #pragma unroll
    for (int i=0;i<5;i++) a += ht[i*16 + c]*w[i];
  }
  out[gid] = a;
}

// --------------------------------------------------------------------------
extern "C" void kernel_launch(void* const* d_in, const int* in_sizes, int n_in,
                              void* d_out, int out_size, void* d_ws, size_t ws_size,
                              hipStream_t stream) {
  const float* x     = (const float*)d_in[0];
  const float* w_in  = (const float*)d_in[1];
  const float* w_out = (const float*)d_in[2];
  const float* wq    = (const float*)d_in[3];
  const float* wk    = (const float*)d_in[4];
  const float* wv    = (const float*)d_in[5];
  const float* wo    = (const float*)d_in[6];
  const float* w1    = (const float*)d_in[7];
  const float* w2    = (const float*)d_in[8];
  float* out = (float*)d_out;

  // carve: h fp32 + qf,kf fp16[64/row] + vf fp16 tiled + nsplit partials
  char* p = (char*)d_ws;
  float* h = (float*)p;              p += (size_t)NTOK*80*4;
  _Float16* qf = (_Float16*)p;       p += (size_t)NTOK*QP*2;
  _Float16* kf = (_Float16*)p;       p += (size_t)NTOK*QP*2;
  _Float16* vf = (_Float16*)p;       p += (size_t)NB*128*VTROWS*32*2;
  size_t fixed = (size_t)((char*)p - (char*)d_ws);
  int nsplit = 4;    // R18-proven best tradeoff
  if (fixed + (size_t)512*4*32*(80+2)*4 > ws_size) nsplit = 2;
  float* wsO = (float*)p;            p += (size_t)512*nsplit*32*80*4;
  float* wsM = (float*)p;            p += (size_t)512*nsplit*32*4;
  float* wsL = (float*)p;

  k_init_qkv<<<NTOK/16, 256, 0, stream>>>(x, w_in, wq, wk, wv, h, qf, kf, vf);
  for (int blk=0; blk<3; ++blk) {
    k_attn_lds<<<128*nsplit, 256, 0, stream>>>(qf, kf, vf, wsO, wsM, wsL, nsplit);
    if (blk < 2) {
      k_merge_mlp_qkv<<<NTOK/16, 256, 0, stream>>>(
          wsO, wsM, wsL, wo+blk*125, w1+blk*250, w2+blk*125,
          wq+(blk+1)*125, wk+(blk+1)*125, wv+(blk+1)*125,
          h, qf, kf, vf, nsplit);
    } else {
      k_merge_mlp<<<NTOK/16, 256, 0, stream>>>(
          wsO, wsM, wsL, wo+blk*125, w1+blk*250, w2+blk*125, h, nsplit);
    }
  }
  k_out<<<(NTOK*35 + 255)/256, 256, 0, stream>>>(h, w_out, out);
}

// Round 21
// 215.732 us; speedup vs baseline: 1.1891x; 1.0183x over previous
//
#include <hip/hip_runtime.h>
#include <hip/hip_bf16.h>
#include <math.h>

typedef __attribute__((ext_vector_type(8)))  _Float16 f16x8;
typedef __attribute__((ext_vector_type(2)))  __fp16   fp16v2;
typedef __attribute__((ext_vector_type(16))) float    f32x16;

// ---------------------------------------------------------------------------
// GATr forward on MI355X. B=4, N=4096, H=5, BLK=3, INV=32, 16 blades.
// R21: R18 attention (LDS-staged K/V, nsplit=4, V slot-swizzle) + full
// fusion chain: k_init_qkv, k_merge_mlp_qkv (x2), k_merge_mlp_out (last
// block merges + MLP + w_out extraction, no h round-trip). 7 launches.
// ---------------------------------------------------------------------------

namespace ga {
constexpr int MASKS[16] = {0,1,2,4,8,3,5,6,9,10,12,7,11,13,14,15};
constexpr int popc4(int x){ return (x&1)+((x>>1)&1)+((x>>2)&1)+((x>>3)&1); }
constexpr int idx_of(int m){ int r=-1; for(int i=0;i<16;i++) if(MASKS[i]==m) r=i; return r; }
struct GPTab {
  int cnt[16];
  signed char ii[16][16];
  signed char jj[16][16];
  float ss[16][16];
};
constexpr GPTab make_gptab(){
  GPTab t{};
  for(int i=0;i<16;i++) for(int j=0;j<16;j++){
    int a=MASKS[i], b=MASKS[j];
    if((a&b&1)!=0) continue;           // e0^2 = 0 kills the term
    int sw=0;
    for(int bi=0;bi<4;bi++) if((b>>bi)&1) sw += popc4(a>>(bi+1));
    int k = idx_of(a^b);
    int c = t.cnt[k];
    t.ii[k][c]=(signed char)i; t.jj[k][c]=(signed char)j;
    t.ss[k][c]=(sw&1)? -1.0f : 1.0f;
    t.cnt[k]=c+1;
  }
  return t;
}
} // namespace ga

__device__ const ga::GPTab GPT = ga::make_gptab();
__constant__ int GRADE16[16] = {0,1,1,1,1,2,2,2,2,2,2,3,3,3,3,4};
__constant__ int CPOS16[16] = {0,-1,1,2,3,-1,-1,4,-1,5,6,-1,-1,-1,7,-1};

#define NTOK 16384   // B*N
#define NSEQ 4096
#define NB 4
#define QP 64        // q/k row stride (40 real feats + pads; 128B rows)
#define VTROWS 80    // v tile rows (feats)
#define THR2 11.54f  // defer-max threshold in log2 domain (= 8 nats)

// --------------------------------------------------------------------------
// Device helper: LN + QKV staging from register h (hv[5] at blade c).
// --------------------------------------------------------------------------
__device__ __forceinline__ void ln_qkv_from_regs(
    const float hv[5], int c, int token,
    const float* __restrict__ wq, const float* __restrict__ wk,
    const float* __restrict__ wv,
    _Float16* __restrict__ qf, _Float16* __restrict__ kf,
    _Float16* __restrict__ vf)
{
  int b = token >> 12;
  int n = token & 4095;
  int vt_tile = b*128 + (n>>5);
  int nn = n & 31;
  int t  = (nn>>2)&3;
  int t2 = ((t<<1)|(t>>1))&3;             // pi: 0,3 fixed; 1<->2
  int vt_col = (nn&3) | (t2<<2) | (nn&16);
  bool inner = (0x469D >> c) & 1;
  float part = 0.f;
  if (inner) {
    #pragma unroll
    for (int i=0;i<5;i++) part += hv[i]*hv[i];
  }
  part += __shfl_xor(part, 1);
  part += __shfl_xor(part, 2);
  part += __shfl_xor(part, 4);
  part += __shfl_xor(part, 8);
  float rinv = 1.f/sqrtf(part*(1.f/80.f) + 1e-6f);
  float rln[5];
  #pragma unroll
  for (int i=0;i<5;i++) rln[i] = hv[i]*rinv;

  int g = GRADE16[c];
  int cp = CPOS16[c];
  const float scaleq = 0.16129820906f;   // (1/sqrt(80)) * log2(e)
  #pragma unroll
  for (int o=0;o<5;o++) {
    const float* wqr = wq + g*25 + o*5;
    const float* wkr = wk + g*25 + o*5;
    const float* wvr = wv + g*25 + o*5;
    float aq=0.f, ak=0.f, av=0.f;
    #pragma unroll
    for (int i=0;i<5;i++) {
      aq += rln[i]*wqr[i];
      ak += rln[i]*wkr[i];
      av += rln[i]*wvr[i];
    }
    vf[((size_t)vt_tile*VTROWS + o*16 + c)*32 + vt_col] = (_Float16)av;
    if (inner) {
      size_t qo = (size_t)token*QP + o*8 + cp;
      qf[qo] = (_Float16)(aq*scaleq);
      kf[qo] = (_Float16)ak;
    }
  }
  if (c < 8) {
    size_t po = (size_t)token*QP + 40 + c;
    qf[po] = (_Float16)0.f;
    kf[po] = (_Float16)0.f;
  }
}

// --------------------------------------------------------------------------
// K1 (FUSED): init h from x + LN + block-0 QKV staging.
// 16 threads/token; the 32-wide scalar dot is distributed across lanes.
// --------------------------------------------------------------------------
__global__ __launch_bounds__(256) void k_init_qkv(
    const float* __restrict__ x, const float* __restrict__ w_in,
    const float* __restrict__ wq, const float* __restrict__ wk,
    const float* __restrict__ wv,
    float* __restrict__ h, _Float16* __restrict__ qf,
    _Float16* __restrict__ kf, _Float16* __restrict__ vf)
{
  int tid = threadIdx.x;
  int c   = tid & 15;
  int token = blockIdx.x*16 + (tid>>4);
  const float* xt = x + (size_t)token*35;
  float* ht = h + (size_t)token*80;

  // distributed 32-dot: lane c covers j = c and c+16 (j=0: mv scalar = 1.0)
  float xa = (c==0) ? 1.f : xt[c];
  float xb = xt[c+16];
  float sv[5];
  #pragma unroll
  for (int o=0;o<5;o++) {
    const float* w0 = w_in + o*32;
    float partial = w0[c]*xa + w0[c+16]*xb;
    partial += __shfl_xor(partial,1);
    partial += __shfl_xor(partial,2);
    partial += __shfl_xor(partial,4);
    partial += __shfl_xor(partial,8);
    sv[o] = partial;
  }
  float hv[5];
  #pragma unroll
  for (int o=0;o<5;o++) {
    float w2c = w_in[2*160 + o*32];
    float v = 0.f;
    if (c==0) v = sv[o];
    else if (c==5) v = w2c*xt[32];
    else if (c==6) v = w2c*xt[33];
    else if (c==8) v = w2c*xt[34];
    hv[o] = v;
    ht[o*16+c] = v;
  }
  ln_qkv_from_regs(hv, c, token, wq, wk, wv, qf, kf, vf);
}

// --------------------------------------------------------------------------
// K3: LDS-staged flash attention (R18: R16 structure + R17 V slot-swizzle).
// Block = 256 thr = 4 waves; each wave owns a DIFFERENT 32-row Q-tile; all
// share the SAME key range. K (4KB) + V (5KB) per tile staged once per
// block, double-buffered, 1 barrier/tile. Swapped QK^T; pi-permuted V.
// V store slot = d ^ ((row>>1)&3). Epilogue: raw per-wave partials.
// --------------------------------------------------------------------------
__global__ __launch_bounds__(256, 2) void k_attn_lds(
    const _Float16* __restrict__ qf, const _Float16* __restrict__ kf,
    const _Float16* __restrict__ vf,
    float* __restrict__ wsO, float* __restrict__ wsM,
    float* __restrict__ wsL, int nsplit)
{
  __shared__ __align__(16) char sK[2][4096];
  __shared__ __align__(16) char sV[2][5120];
  __shared__ __align__(16) float sF[4][32];
  int tid = threadIdx.x;
  int w  = tid >> 6;
  int l  = tid & 63;
  int ln = l & 31;
  int hf = l >> 5;
  int bid = blockIdx.x;
  int xcd = bid & 7;
  int b   = xcd & 3;
  int rest = bid >> 3;
  int qlo  = rest & 15;
  int z    = rest >> 4;
  int qgroup = (xcd>>2)*16 + qlo;
  int qtile = qgroup*4 + w;
  int rowbase = b*NSEQ + qtile*32;
  int ntiles = (NSEQ/nsplit) >> 5;
  int kbeg = z*(NSEQ/nsplit);

  const _Float16* qp = qf + (size_t)(rowbase + ln)*QP + hf*8;
  f16x8 q0 = *(const f16x8*)(qp);
  f16x8 q1 = *(const f16x8*)(qp + 16);
  f16x8 q2 = *(const f16x8*)(qp + 32);

  f32x16 acc0, acc1, acc2;
  #pragma unroll
  for (int r=0;r<16;r++){ acc0[r]=0.f; acc1[r]=0.f; acc2[r]=0.f; }
  float m = -1e30f, lsum = 0.f;

  int rdK0 = ln*128 + (((0+hf)^(ln&7))<<4);
  int rdK1 = ln*128 + (((2+hf)^(ln&7))<<4);
  int rdK2 = ln*128 + (((4+hf)^(ln&7))<<4);
  int vr0 = ln, vr1 = 32+ln, vr2 = 64+(ln&15);
  int sw0 = (vr0>>1)&3, sw1 = (vr1>>1)&3, sw2 = (vr2>>1)&3;
  int rdV00 = vr0*64 + (((hf  )^sw0)<<4);
  int rdV01 = vr0*64 + (((hf+2)^sw0)<<4);
  int rdV10 = vr1*64 + (((hf  )^sw1)<<4);
  int rdV11 = vr1*64 + (((hf+2)^sw1)<<4);
  int rdV20 = vr2*64 + (((hf  )^sw2)<<4);
  int rdV21 = vr2*64 + (((hf+2)^sw2)<<4);

  const _Float16* kfb = kf + (size_t)b*NSEQ*QP;
  const _Float16* vfb = vf + (size_t)(b*128)*(VTROWS*32);

  {
    const float4* kT = (const float4*)(kfb + (size_t)kbeg*QP);
    const float4* vT = (const float4*)(vfb + (size_t)(kbeg>>5)*(VTROWS*32));
    #pragma unroll
    for (int i=w; i<9; i+=4) {
      float4 d = (i<4) ? kT[i*64 + l] : vT[(i-4)*64 + l];
      if (i<4) {
        int gid = i*64 + l;
        *(float4*)(sK[0] + ((gid>>3)*128 + (((gid&7)^((gid>>3)&7))<<4))) = d;
      } else {
        int gid = (i-4)*64 + l;
        *(float4*)(sV[0] + ((gid>>2)*64 + (((gid&3)^((gid>>3)&3))<<4))) = d;
      }
    }
  }
  __syncthreads();

  for (int t=0; t<ntiles; ++t) {
    int cur = t & 1;
    float4 stg0, stg1, stg2; int i2=-1;
    if (t+1 < ntiles) {
      int koffn = kbeg + (t+1)*32;
      const float4* kT = (const float4*)(kfb + (size_t)koffn*QP);
      const float4* vT = (const float4*)(vfb + (size_t)(koffn>>5)*(VTROWS*32));
      stg0 = kT[w*64+l];
      stg1 = vT[w*64+l];
      if (w==0) { i2 = 8; stg2 = vT[4*64+l]; }
    }

    f16x8 kc0 = *(const f16x8*)(sK[cur] + rdK0);
    f16x8 kc1 = *(const f16x8*)(sK[cur] + rdK1);
    f16x8 kc2 = *(const f16x8*)(sK[cur] + rdK2);

    f32x16 S;
    #pragma unroll
    for (int r=0;r<16;r++) S[r]=0.f;
    S = __builtin_amdgcn_mfma_f32_32x32x16_f16(kc0, q0, S, 0,0,0);
    S = __builtin_amdgcn_mfma_f32_32x32x16_f16(kc1, q1, S, 0,0,0);
    S = __builtin_amdgcn_mfma_f32_32x32x16_f16(kc2, q2, S, 0,0,0);

    float t01 = fmaxf(S[0],S[1]),   t23 = fmaxf(S[2],S[3]);
    float t45 = fmaxf(S[4],S[5]),   t67 = fmaxf(S[6],S[7]);
    float t89 = fmaxf(S[8],S[9]),   tab = fmaxf(S[10],S[11]);
    float tcd = fmaxf(S[12],S[13]), tef = fmaxf(S[14],S[15]);
    float u0 = fmaxf(t01,t23), u1 = fmaxf(t45,t67);
    float u2 = fmaxf(t89,tab), u3 = fmaxf(tcd,tef);
    float tmax = fmaxf(fmaxf(u0,u1), fmaxf(u2,u3));
    tmax = fmaxf(tmax, __shfl_xor(tmax, 32));
    if (!__all(tmax <= m + THR2)) {
      float mn = fmaxf(m, tmax);
      float f = exp2f(m - mn);
      lsum *= f;
      m = mn;
      if (hf==0) sF[w][ln] = f;
      float fv[16];
      *(float4*)&fv[0]  = *(const float4*)&sF[w][ 0 + hf*4];
      *(float4*)&fv[4]  = *(const float4*)&sF[w][ 8 + hf*4];
      *(float4*)&fv[8]  = *(const float4*)&sF[w][16 + hf*4];
      *(float4*)&fv[12] = *(const float4*)&sF[w][24 + hf*4];
      #pragma unroll
      for (int r=0;r<16;r++){ float fr=fv[r]; acc0[r]*=fr; acc1[r]*=fr; acc2[r]*=fr; }
    }
    float p[16];
    #pragma unroll
    for (int r=0;r<16;r++) p[r] = exp2f(S[r] - m);
    float s0 = (p[0]+p[1]) + (p[2]+p[3]);
    float s1 = (p[4]+p[5]) + (p[6]+p[7]);
    float s2 = (p[8]+p[9]) + (p[10]+p[11]);
    float s3 = (p[12]+p[13]) + (p[14]+p[15]);
    lsum += (s0+s1) + (s2+s3);

    union { unsigned u[4]; f16x8 v; } A0, A1;
    #pragma unroll
    for (int e=0;e<4;e++) {
      union { fp16v2 h2; unsigned u; } cv;
      cv.h2 = __builtin_amdgcn_cvt_pkrtz(p[2*e], p[2*e+1]);
      A0.u[e] = cv.u;
    }
    #pragma unroll
    for (int e=0;e<4;e++) {
      union { fp16v2 h2; unsigned u; } cv;
      cv.h2 = __builtin_amdgcn_cvt_pkrtz(p[8+2*e], p[9+2*e]);
      A1.u[e] = cv.u;
    }

    f16x8 vc00 = *(const f16x8*)(sV[cur] + rdV00);
    f16x8 vc01 = *(const f16x8*)(sV[cur] + rdV01);
    f16x8 vc10 = *(const f16x8*)(sV[cur] + rdV10);
    f16x8 vc11 = *(const f16x8*)(sV[cur] + rdV11);
    f16x8 vc20 = *(const f16x8*)(sV[cur] + rdV20);
    f16x8 vc21 = *(const f16x8*)(sV[cur] + rdV21);

    acc0 = __builtin_amdgcn_mfma_f32_32x32x16_f16(A0.v, vc00, acc0, 0,0,0);
    acc0 = __builtin_amdgcn_mfma_f32_32x32x16_f16(A1.v, vc01, acc0, 0,0,0);
    acc1 = __builtin_amdgcn_mfma_f32_32x32x16_f16(A0.v, vc10, acc1, 0,0,0);
    acc1 = __builtin_amdgcn_mfma_f32_32x32x16_f16(A1.v, vc11, acc1, 0,0,0);
    acc2 = __builtin_amdgcn_mfma_f32_32x32x16_f16(A0.v, vc20, acc2, 0,0,0);
    acc2 = __builtin_amdgcn_mfma_f32_32x32x16_f16(A1.v, vc21, acc2, 0,0,0);

    if (t+1 < ntiles) {
      int nxt = (t+1) & 1;
      {
        int gid = w*64 + l;
        *(float4*)(sK[nxt] + ((gid>>3)*128 + (((gid&7)^((gid>>3)&7))<<4))) = stg0;
      }
      {
        int gid = w*64 + l;
        *(float4*)(sV[nxt] + ((gid>>2)*64 + (((gid&3)^((gid>>3)&3))<<4))) = stg1;
      }
      if (i2 == 8) {
        int gid = 4*64 + l;
        *(float4*)(sV[nxt] + ((gid>>2)*64 + (((gid&3)^((gid>>3)&3))<<4))) = stg2;
      }
    }
    __syncthreads();
  }

  lsum += __shfl_xor(lsum, 32);

  int pidx = (b*128 + qtile)*nsplit + z;
  if (hf==0) {
    wsM[pidx*32 + ln] = m;
    wsL[pidx*32 + ln] = lsum;
  }
  float* po = wsO + (size_t)pidx*32*80;
  #pragma unroll
  for (int r=0;r<16;r++) {
    int row = (r&3) + 8*(r>>2) + 4*hf;
    po[row*80 + ln]      = acc0[r];
    po[row*80 + 32 + ln] = acc1[r];
    if (ln < 16) po[row*80 + 64 + ln] = acc2[r];
  }
}

// --------------------------------------------------------------------------
// Device helper: merge + wo-proj + residual + LN + MLP -> newh[5].
// WRITE_H: whether to store newh back to h (skipped in the final block).
// --------------------------------------------------------------------------
template<bool WRITE_H>
__device__ __forceinline__ void merge_mlp_body(
    const float* __restrict__ wsO, const float* __restrict__ wsM,
    const float* __restrict__ wsL, const float* __restrict__ wo,
    const float* __restrict__ w1, const float* __restrict__ w2,
    float* __restrict__ h, int nsplit,
    float (*sh1)[10][16], int tid, float newh[5])
{
  int c   = tid & 15;
  int tl  = tid >> 4;
  int token = blockIdx.x*16 + tl;
  int qrow = token & 31;
  int qt   = token >> 5;
  int g = GRADE16[c];
  float* ht = h + (size_t)token*80;

  int base = qt*nsplit;
  float M = -1e30f;
  for (int s=0; s<nsplit; ++s) M = fmaxf(M, wsM[(base+s)*32 + qrow]);
  float wgt[8];
  float L = 0.f;
  for (int s=0; s<nsplit; ++s) {
    wgt[s] = exp2f(wsM[(base+s)*32 + qrow] - M);
    L += wgt[s]*wsL[(base+s)*32 + qrow];
  }
  float invL = 1.f/L;
  float att[5];
  #pragma unroll
  for (int i=0;i<5;i++) {
    float a = 0.f;
    for (int s=0; s<nsplit; ++s)
      a += wgt[s]*wsO[((size_t)(base+s)*32 + qrow)*80 + i*16 + c];
    att[i] = a*invL;
  }

  float hv[5];
  #pragma unroll
  for (int o=0;o<5;o++) {
    const float* wor = wo + g*25 + o*5;
    float a = 0.f;
    #pragma unroll
    for (int i=0;i<5;i++) a += att[i]*wor[i];
    hv[o] = ht[o*16 + c] + a;
  }

  bool inner = (0x469D >> c) & 1;
  float part = 0.f;
  if (inner) {
    #pragma unroll
    for (int i=0;i<5;i++) part += hv[i]*hv[i];
  }
  part += __shfl_xor(part, 1);
  part += __shfl_xor(part, 2);
  part += __shfl_xor(part, 4);
  part += __shfl_xor(part, 8);
  float rinv = 1.f/sqrtf(part*(1.f/80.f) + 1e-6f);
  float rln[5];
  #pragma unroll
  for (int i=0;i<5;i++) rln[i] = hv[i]*rinv;

  #pragma unroll
  for (int o=0;o<10;o++) {
    const float* w1r = w1 + g*50 + o*5;
    float a=0.f;
    #pragma unroll
    for (int i=0;i<5;i++) a += rln[i]*w1r[i];
    sh1[tl][o][c] = a;
  }
  __syncthreads();
  float gpv[5];
  #pragma unroll
  for (int hh=0; hh<5; hh++) {
    float a = 0.f;
    int n = GPT.cnt[c];
    for (int e=0; e<n; ++e) {
      a += GPT.ss[c][e]*sh1[tl][hh][GPT.ii[c][e]]*sh1[tl][5+hh][GPT.jj[c][e]];
    }
    gpv[hh] = a;
  }
  int lbase = (tid & 63) & ~15;
  #pragma unroll
  for (int hh=0;hh<5;hh++) {
    float g0 = __shfl(gpv[hh], lbase);
    float u  = 0.7978845608028654f*(g0 + 0.044715f*g0*g0*g0);
    float gate = 0.5f*g0*(1.f + tanhf(u));
    gpv[hh] *= gate;
  }
  #pragma unroll
  for (int o=0;o<5;o++) {
    const float* w2r = w2 + g*25 + o*5;
    float a=0.f;
    #pragma unroll
    for (int i=0;i<5;i++) a += gpv[i]*w2r[i];
    newh[o] = hv[o] + a;
    if (WRITE_H) ht[o*16+c] = newh[o];
  }
}

// --------------------------------------------------------------------------
// K4a (FUSED): merge+MLP + next-block LN+QKV staging.
// --------------------------------------------------------------------------
__global__ __launch_bounds__(256) void k_merge_mlp_qkv(
    const float* __restrict__ wsO, const float* __restrict__ wsM,
    const float* __restrict__ wsL, const float* __restrict__ wo,
    const float* __restrict__ w1, const float* __restrict__ w2,
    const float* __restrict__ wqn, const float* __restrict__ wkn,
    const float* __restrict__ wvn,
    float* __restrict__ h, _Float16* __restrict__ qf,
    _Float16* __restrict__ kf, _Float16* __restrict__ vf, int nsplit)
{
  __shared__ float sh1[16][10][16];
  int tid = threadIdx.x;
  float newh[5];
  merge_mlp_body<true>(wsO, wsM, wsL, wo, w1, w2, h, nsplit, sh1, tid, newh);
  int c = tid & 15;
  int token = blockIdx.x*16 + (tid>>4);
  ln_qkv_from_regs(newh, c, token, wqn, wkn, wvn, qf, kf, vf);
}

// --------------------------------------------------------------------------
// K4b (FUSED, last block): merge+MLP + final w_out projection + extraction.
// out[token][0..31] = sum_i newh_at_blade0[i]*w_out[j*5+i] (via lane bcast);
// out[token][32..34] = vector blades 5,6,8 of channel-0 row of grade-2 w_out.
// --------------------------------------------------------------------------
__global__ __launch_bounds__(256) void k_merge_mlp_out(
    const float* __restrict__ wsO, const float* __restrict__ wsM,
    const float* __restrict__ wsL, const float* __restrict__ wo,
    const float* __restrict__ w1, const float* __restrict__ w2,
    const float* __restrict__ w_out,
    float* __restrict__ h, float* __restrict__ out, int nsplit)
{
  __shared__ float sh1[16][10][16];
  int tid = threadIdx.x;
  float newh[5];
  merge_mlp_body<false>(wsO, wsM, wsL, wo, w1, w2, h, nsplit, sh1, tid, newh);
  int c = tid & 15;
  int token = blockIdx.x*16 + (tid>>4);
  int lbase = (tid & 63) & ~15;
  // broadcast blade-0 components of all 5 channels to all 16 lanes
  float h0[5];
  #pragma unroll
  for (int i=0;i<5;i++) h0[i] = __shfl(newh[i], lbase);
  float* ot = out + (size_t)token*35;
  // scalars: lane c emits j=c and j=c+16
  {
    const float* wr = w_out + c*5;
    float a=0.f;
    #pragma unroll
    for (int i=0;i<5;i++) a += h0[i]*wr[i];
    ot[c] = a;
    const float* wr2 = w_out + (c+16)*5;
    float a2=0.f;
    #pragma unroll
    for (int i=0;i<5;i++) a2 += h0[i]*wr2[i];
    ot[c+16] = a2;
  }
  // vector: lanes 5,6,8 hold blades 5,6,8 -> out 32,33,34
  if (c==5 || c==6 || c==8) {
    const float* wv2 = w_out + 2*160;   // grade-2, out-channel 0
    float a=0.f;
    #pragma unroll
    for (int i=0;i<5;i++) a += newh[i]*wv2[i];
    int j = (c==5)?32:((c==6)?33:34);
    ot[j] = a;
  }
}

// --------------------------------------------------------------------------
extern "C" void kernel_launch(void* const* d_in, const int* in_sizes, int n_in,
                              void* d_out, int out_size, void* d_ws, size_t ws_size,
                              hipStream_t stream) {
  const float* x     = (const float*)d_in[0];
  const float* w_in  = (const float*)d_in[1];
  const float* w_out = (const float*)d_in[2];
  const float* wq    = (const float*)d_in[3];
  const float* wk    = (const float*)d_in[4];
  const float* wv    = (const float*)d_in[5];
  const float* wo    = (const float*)d_in[6];
  const float* w1    = (const float*)d_in[7];
  const float* w2    = (const float*)d_in[8];
  float* out = (float*)d_out;

  // carve: h fp32 + qf,kf fp16[64/row] + vf fp16 tiled + nsplit partials
  char* p = (char*)d_ws;
  float* h = (float*)p;              p += (size_t)NTOK*80*4;
  _Float16* qf = (_Float16*)p;       p += (size_t)NTOK*QP*2;
  _Float16* kf = (_Float16*)p;       p += (size_t)NTOK*QP*2;
  _Float16* vf = (_Float16*)p;       p += (size_t)NB*128*VTROWS*32*2;
  size_t fixed = (size_t)((char*)p - (char*)d_ws);
  int nsplit = 4;    // R18-proven best tradeoff
  if (fixed + (size_t)512*4*32*(80+2)*4 > ws_size) nsplit = 2;
  float* wsO = (float*)p;            p += (size_t)512*nsplit*32*80*4;
  float* wsM = (float*)p;            p += (size_t)512*nsplit*32*4;
  float* wsL = (float*)p;

  k_init_qkv<<<NTOK/16, 256, 0, stream>>>(x, w_in, wq, wk, wv, h, qf, kf, vf);
  for (int blk=0; blk<3; ++blk) {
    k_attn_lds<<<128*nsplit, 256, 0, stream>>>(qf, kf, vf, wsO, wsM, wsL, nsplit);
    if (blk < 2) {
      k_merge_mlp_qkv<<<NTOK/16, 256, 0, stream>>>(
          wsO, wsM, wsL, wo+blk*125, w1+blk*250, w2+blk*125,
          wq+(blk+1)*125, wk+(blk+1)*125, wv+(blk+1)*125,
          h, qf, kf, vf, nsplit);
    } else {
      k_merge_mlp_out<<<NTOK/16, 256, 0, stream>>>(
          wsO, wsM, wsL, wo+blk*125, w1+blk*250, w2+blk*125,
          w_out, h, out, nsplit);
    }
  }
}